// Round 8
// baseline (237.911 us; speedup 1.0000x reference)
//
#include <hip/hip_runtime.h>
#include <stdint.h>

// VSampling R17 (= R16 resubmitted after infra flake "container failed twice";
// no kernel changes -- audit found no hang/fault candidates vs passing R15).
//  - k_emit2: word-parallel emit (thread w walks mask[w] via __ffs, emits its
//    popc CONSECUTIVE ranks from wrank[w]) -- removes the 9-dependent-LDS-read
//    binary search per rank. 512 threads + DENSE_MAX 4096 (36KB LDS) -> 4
//    blocks/CU (32 waves vs 16). Single-segment fast path (vc<=DENSE_MAX skips
//    range checks; typical vc~1800).
//  - k_scanrow / k_scan2048(b): shfl wave scans (16/20 barriers -> 2).
// HW rules (measured): per-point global atomics = poison (R11/R13);
// wide-grid __threadfence = poison (R14); LDS atomics fine.
// Keys bit-exact vs ref: IEEE fp32 (c - s)/0.05f + floorf (no fast-math).

typedef unsigned int uint;
typedef unsigned long long u64;

#define VS 0.05f
#define QSCALE (4096.0f / VS)
#define QINV  (VS / 4096.0f)
#define NBUCKET 2048          // B(<=16) * 128
#define NBLK_P 256
#define DENSE_MAX 4096        // emit rank-segment size (32KB LDS)

__device__ __forceinline__ uint f2m(float f) {
    uint b = __float_as_uint(f);
    return (b & 0x80000000u) ? ~b : (b | 0x80000000u);
}
__device__ __forceinline__ float m2f(uint m) {
    uint b = (m & 0x80000000u) ? (m & 0x7fffffffu) : ~m;
    return __uint_as_float(b);
}

__global__ void k_init(uint* start_m, int B3) {
    int i = blockIdx.x * blockDim.x + threadIdx.x;
    if (i < B3) start_m[i] = 0xFFFFFFFFu;
}

// per-batch MIN of each coord axis (R10 version, measured-good).
__global__ void __launch_bounds__(256)
k_minmax(const float* __restrict__ coord, const int* __restrict__ offset,
         int N, int B, uint* start_m) {
    __shared__ uint smin[768];
    __shared__ int soff[256];
    int t = threadIdx.x;
    int nb3 = B * 3;
    for (int j = t; j < B; j += 256) soff[j] = offset[j];
    for (int j = t; j < nb3; j += 256) smin[j] = 0xFFFFFFFFu;
    __syncthreads();

    int F = 3 * N;
    int NQ = F >> 2;
    int per = (NQ + gridDim.x - 1) / gridDim.x;
    int qlo = blockIdx.x * per;
    int qhi = min(NQ, qlo + per);
    const float4* __restrict__ c4 = reinterpret_cast<const float4*>(coord);

    bool fast = false;
    int bU = 0;
    if (qlo < qhi) {
        int pF = (4 * qlo) / 3;
        int pL = (4 * qhi - 1) / 3;
        int bF = 0, bL = 0;
        for (int j = 0; j < B; ++j) {
            bF += (pF >= soff[j]) ? 1 : 0;
            bL += (pL >= soff[j]) ? 1 : 0;
        }
        fast = (bF == bL);
        bU = bF;
    }

    if (fast) {
        int q = qlo + t;
        int p0 = q % 3;
        float s0 = INFINITY, s1 = INFINITY, s2 = INFINITY;
        for (;;) {
            if (q >= qhi) break;
            float4 v = c4[q];
            s0 = fminf(s0, fminf(v.x, v.w)); s1 = fminf(s1, v.y); s2 = fminf(s2, v.z);
            q += 256;
            if (q >= qhi) break;
            v = c4[q];
            s1 = fminf(s1, fminf(v.x, v.w)); s2 = fminf(s2, v.y); s0 = fminf(s0, v.z);
            q += 256;
            if (q >= qhi) break;
            v = c4[q];
            s2 = fminf(s2, fminf(v.x, v.w)); s0 = fminf(s0, v.y); s1 = fminf(s1, v.z);
            q += 256;
        }
        float ax, ay, az;
        if (p0 == 0)      { ax = s0; ay = s1; az = s2; }
        else if (p0 == 1) { ax = s2; ay = s0; az = s1; }
        else              { ax = s1; ay = s2; az = s0; }
        for (int d = 32; d; d >>= 1) {
            ax = fminf(ax, __shfl_xor(ax, d));
            ay = fminf(ay, __shfl_xor(ay, d));
            az = fminf(az, __shfl_xor(az, d));
        }
        if ((t & 63) == 0 && ax < INFINITY) {
            atomicMin(&smin[bU * 3 + 0], f2m(ax));
            atomicMin(&smin[bU * 3 + 1], f2m(ay));
            atomicMin(&smin[bU * 3 + 2], f2m(az));
        }
    } else {
        for (int q = qlo + t; q < qhi; q += 256) {
            float4 v = c4[q];
            int e = 4 * q;
            float vals[4] = {v.x, v.y, v.z, v.w};
#pragma unroll
            for (int k = 0; k < 4; ++k) {
                int ee = e + k;
                int pt = ee / 3;
                int axis = ee - 3 * pt;
                int b = 0;
                for (int j = 0; j < B; ++j) b += (pt >= soff[j]) ? 1 : 0;
                atomicMin(&smin[b * 3 + axis], f2m(vals[k]));
            }
        }
    }

    if (blockIdx.x == 0) {
        for (int ee = 4 * NQ + t; ee < F; ee += 256) {
            int pt = ee / 3;
            int axis = ee - 3 * pt;
            int b = 0;
            for (int j = 0; j < B; ++j) b += (pt >= soff[j]) ? 1 : 0;
            atomicMin(&smin[b * 3 + axis], f2m(coord[ee]));
        }
    }
    __syncthreads();
    for (int j = t; j < nb3; j += 256) {
        uint mn = smin[j];
        if (mn != 0xFFFFFFFFu) atomicMin(&start_m[j], mn);
    }
}

// ---------------- partition pipeline ----------------

// full record for one point: [q:11 | cell:14 | ux:12 | uy:12 | uz:12]
__device__ __forceinline__ u64 mk_rec(float x, float y, float z,
                                      float sx, float sy, float sz,
                                      int b, uint& q) {
    int gx = min((int)floorf((x - sx) / VS), 127);
    int gy = min((int)floorf((y - sy) / VS), 127);
    int gz = min((int)floorf((z - sz) / VS), 127);
    float fx = fmaxf(x - (sx + (float)gx * VS), 0.0f);
    float fy = fmaxf(y - (sy + (float)gy * VS), 0.0f);
    float fz = fmaxf(z - (sz + (float)gz * VS), 0.0f);
    uint ux = min((uint)(fx * QSCALE + 0.5f), 4095u);
    uint uy = min((uint)(fy * QSCALE + 0.5f), 4095u);
    uint uz = min((uint)(fz * QSCALE + 0.5f), 4095u);
    uint cell = ((uint)gy << 7) | (uint)gz;
    q = ((uint)b << 7) | (uint)gx;
    return ((u64)q << 50) | ((u64)cell << 36) | ((u64)ux << 24) | ((u64)uy << 12) | (u64)uz;
}

__device__ __forceinline__ void count_point(float x, float y, float z, int b,
                                            float sx, float sy, float sz, int pid,
                                            uint* hist, u64* __restrict__ tmp) {
    uint q;
    u64 rec = mk_rec(x, y, z, sx, sy, sz, b, q);
    atomicAdd(&hist[q], 1u);        // LDS atomic only
    tmp[pid] = rec;                 // coalesced
}

// per-block LDS histogram -> TRANSPOSED histm[bucket][block]; writes tagged
// records coalesced to tmp. No global atomics.
__global__ void __launch_bounds__(1024)
k_count3(const float* __restrict__ coord, const int* __restrict__ offset,
         int N, int B, const uint* __restrict__ start_m, uint* __restrict__ histm,
         u64* __restrict__ tmp) {
    __shared__ uint hist[NBUCKET];
    __shared__ int soff[16];
    __shared__ float sstart[48];
    int t = threadIdx.x;
    if (t < B) soff[t] = offset[t];
    if (t < B * 3) sstart[t] = m2f(start_m[t]);
    for (int j = t; j < NBUCKET; j += 1024) hist[j] = 0;
    __syncthreads();
    int chunk = (N + gridDim.x - 1) / gridDim.x;
    int lo = blockIdx.x * chunk, hi = min(N, lo + chunk);
    int bLo = 0, bHi = 0;
    for (int j = 0; j < B; ++j) {
        bLo += (lo >= soff[j]) ? 1 : 0;
        bHi += (hi - 1 >= soff[j]) ? 1 : 0;
    }
    if (lo < hi && bLo == bHi && (lo & 3) == 0) {
        int b = bLo;
        float sx = sstart[b * 3 + 0], sy = sstart[b * 3 + 1], sz = sstart[b * 3 + 2];
        const float4* __restrict__ c4 = reinterpret_cast<const float4*>(coord);
        int gEnd = hi >> 2;
        for (int g = (lo >> 2) + t; g < gEnd; g += 1024) {
            float4 v0 = c4[3 * g], v1 = c4[3 * g + 1], v2 = c4[3 * g + 2];
            int p = 4 * g;
            count_point(v0.x, v0.y, v0.z, b, sx, sy, sz, p + 0, hist, tmp);
            count_point(v0.w, v1.x, v1.y, b, sx, sy, sz, p + 1, hist, tmp);
            count_point(v1.z, v1.w, v2.x, b, sx, sy, sz, p + 2, hist, tmp);
            count_point(v2.y, v2.z, v2.w, b, sx, sy, sz, p + 3, hist, tmp);
        }
        for (int i = (gEnd << 2) + t; i < hi; i += 1024) {
            float x = coord[3 * i + 0], y = coord[3 * i + 1], z = coord[3 * i + 2];
            count_point(x, y, z, b, sx, sy, sz, i, hist, tmp);
        }
    } else {
        for (int i = lo + t; i < hi; i += 1024) {
            float x = coord[3 * i + 0], y = coord[3 * i + 1], z = coord[3 * i + 2];
            int b = 0;
            for (int j = 0; j < B; ++j) b += (i >= soff[j]) ? 1 : 0;
            count_point(x, y, z, b, sstart[b * 3 + 0], sstart[b * 3 + 1],
                        sstart[b * 3 + 2], i, hist, tmp);
        }
    }
    __syncthreads();
    for (int j = t; j < NBUCKET; j += 1024)
        histm[(size_t)j * NBLK_P + blockIdx.x] = hist[j];
}

// per-bucket row scan (256 values): exclusive prefix in place + row total.
// shfl wave scan: 2 barriers.
__global__ void __launch_bounds__(256)
k_scanrow(uint* __restrict__ histm, uint* __restrict__ tot) {
    __shared__ uint wtot[4], woff[4];
    uint* row = histm + (size_t)blockIdx.x * NBLK_P;
    int t = threadIdx.x;
    uint v = row[t];
    uint sc = v;
    for (int d = 1; d < 64; d <<= 1) {
        uint nb = __shfl_up(sc, d, 64);
        if ((t & 63) >= d) sc += nb;
    }
    if ((t & 63) == 63) wtot[t >> 6] = sc;
    __syncthreads();
    if (t == 0) {
        uint r = 0;
#pragma unroll
        for (int k = 0; k < 4; ++k) { woff[k] = r; r += wtot[k]; }
    }
    __syncthreads();
    uint incl = sc + woff[t >> 6];
    row[t] = incl - v;
    if (t == 255) tot[blockIdx.x] = incl;
}

// exclusive scan of 2048 values -> out[0..2047], out[2048]=total. shfl scan.
__global__ void __launch_bounds__(1024)
k_scan2048(const uint* __restrict__ in, uint* __restrict__ out) {
    __shared__ uint wtot[16], woff[16];
    int t = threadIdx.x;
    uint a = in[2 * t], bb = in[2 * t + 1];
    uint s = a + bb;
    uint sc = s;
    for (int d = 1; d < 64; d <<= 1) {
        uint nb = __shfl_up(sc, d, 64);
        if ((t & 63) >= d) sc += nb;
    }
    if ((t & 63) == 63) wtot[t >> 6] = sc;
    __syncthreads();
    if (t == 0) {
        uint r = 0;
#pragma unroll
        for (int k = 0; k < 16; ++k) { woff[k] = r; r += wtot[k]; }
    }
    __syncthreads();
    uint incl = sc + woff[t >> 6];
    uint ex = incl - s;
    out[2 * t] = ex;
    out[2 * t + 1] = ex + a;
    if (t == 1023) out[2048] = incl;
}

// scan variant for voxcount -> voxscan, with n_o fused.
__global__ void __launch_bounds__(1024)
k_scan2048b(const uint* __restrict__ in, uint* __restrict__ out,
            int B, float* __restrict__ no_out) {
    __shared__ uint wtot[16], woff[16];
    int t = threadIdx.x;
    uint a = in[2 * t], bb = in[2 * t + 1];
    uint s = a + bb;
    uint sc = s;
    for (int d = 1; d < 64; d <<= 1) {
        uint nb = __shfl_up(sc, d, 64);
        if ((t & 63) >= d) sc += nb;
    }
    if ((t & 63) == 63) wtot[t >> 6] = sc;
    __syncthreads();
    if (t == 0) {
        uint r = 0;
#pragma unroll
        for (int k = 0; k < 16; ++k) { woff[k] = r; r += wtot[k]; }
    }
    __syncthreads();
    uint incl = sc + woff[t >> 6];
    uint ex = incl - s;
    out[2 * t] = ex;
    out[2 * t + 1] = ex + a;
    if (t == 1023) out[2048] = incl;
    int tp = t + 1;
    if ((tp & 63) == 0) {              // incl covers elements [0, 2*tp)
        int b = (tp >> 6) - 1;         // 2*tp == (b+1)*128
        if (b < B) no_out[b] = (float)incl;
    }
}

// scatter tagged records from tmp (L2/L3-resident) to bucket-grouped recs
__global__ void __launch_bounds__(1024)
k_scatter(const u64* __restrict__ tmp, int N,
          const uint* __restrict__ histm, const uint* __restrict__ bucket_base,
          u64* __restrict__ recs) {
    __shared__ uint cursor[NBUCKET];
    int t = threadIdx.x;
    for (int j = t; j < NBUCKET; j += 1024)
        cursor[j] = bucket_base[j] + histm[(size_t)j * NBLK_P + blockIdx.x];
    __syncthreads();
    int chunk = (N + gridDim.x - 1) / gridDim.x;
    int lo = blockIdx.x * chunk, hi = min(N, lo + chunk);
    for (int i = lo + t; i < hi; i += 1024) {
        u64 r = tmp[i];
        uint q = (uint)(r >> 50);
        uint slot = atomicAdd(&cursor[q], 1u);   // LDS atomic only
        recs[slot] = r;
    }
}

// per-bucket occupancy: voxcount + store mask to global (recs read = L3 hit).
__global__ void k_vox(const u64* __restrict__ recs, const uint* __restrict__ bucket_base,
                      uint* __restrict__ voxcount, uint* __restrict__ gmask) {
    __shared__ uint bits[512];
    __shared__ uint wsum[4];
    int q = blockIdx.x;
    uint lo = bucket_base[q], hi = bucket_base[q + 1];
    for (int j = threadIdx.x; j < 512; j += blockDim.x) bits[j] = 0;
    __syncthreads();
    for (uint i = lo + threadIdx.x; i < hi; i += blockDim.x) {
        uint c = (uint)(recs[i] >> 36) & 0x3FFFu;
        atomicOr(&bits[c >> 5], 1u << (c & 31));   // LDS atomic only
    }
    __syncthreads();
    uint s = 0;
    for (int w = threadIdx.x; w < 512; w += blockDim.x) {
        uint m = bits[w];
        gmask[(size_t)q * 512 + w] = m;
        s += __popc(m);
    }
    for (int d = 32; d; d >>= 1) s += __shfl_xor(s, d);
    if ((threadIdx.x & 63) == 0) wsum[threadIdx.x >> 6] = s;
    __syncthreads();
    if (threadIdx.x == 0) voxcount[q] = wsum[0] + wsum[1] + wsum[2] + wsum[3];
}

// rank-dense emit (blocks < NBUCKET) + fused output-tail zeroing (blocks >=
// NBUCKET). 512 threads, DENSE_MAX 4096 -> 36KB LDS, 4 blocks/CU (32 waves).
// Word-parallel emit: thread w emits its popc consecutive ranks (no search).
__global__ void __launch_bounds__(512)
k_emit2(const u64* __restrict__ recs, const uint* __restrict__ bucket_base,
        const uint* __restrict__ voxscan, const uint* __restrict__ gmask,
        const uint* __restrict__ start_m, int N, int B, int out_total,
        float* __restrict__ np_out, float* __restrict__ cnt_out,
        float* __restrict__ out) {
    int t = threadIdx.x;
    if (blockIdx.x >= NBUCKET) {
        uint total = voxscan[NBUCKET];
        int zb = blockIdx.x - NBUCKET;
        int stride = (gridDim.x - NBUCKET) * 512;
        int tid = zb * 512 + t;
        for (int j = 3 * (int)total + tid; j < 3 * N; j += stride) np_out[j] = 0.0f;
        for (int j = (int)total + tid; j < N; j += stride) cnt_out[j] = 0.0f;
        for (int j = 4 * N + B + tid; j < out_total; j += stride) out[j] = 0.0f;
        return;
    }
    __shared__ u64 dense[DENSE_MAX];    // 32 KB
    __shared__ uint mask[512], wrank[512];
    __shared__ uint wtot[8], woff[9];
    __shared__ float sstart[48];
    int q = blockIdx.x;
    uint lo = bucket_base[q], hi = bucket_base[q + 1];
    if (lo == hi) return;
    if (t < 48) sstart[t] = m2f(start_m[t]);
    uint m = gmask[(size_t)q * 512 + t];
    mask[t] = m;
    uint c = __popc(m);
    uint sc = c;
    for (int d = 1; d < 64; d <<= 1) {
        uint nb = __shfl_up(sc, d, 64);
        if ((t & 63) >= d) sc += nb;
    }
    if ((t & 63) == 63) wtot[t >> 6] = sc;
    __syncthreads();
    if (t == 0) {
        uint r = 0;
#pragma unroll
        for (int k = 0; k < 8; ++k) { woff[k] = r; r += wtot[k]; }
        woff[8] = r;
    }
    __syncthreads();
    wrank[t] = sc - c + woff[t >> 6];   // exclusive word rank
    uint vc = woff[8];
    uint base_r = voxscan[q];
    int b = q >> 7, gx = q & 127;
    float cx = sstart[b * 3 + 0] + (float)gx * VS;
    float sy = sstart[b * 3 + 1], sz = sstart[b * 3 + 2];
    bool single = (vc <= (uint)DENSE_MAX);
    for (uint segbase = 0; segbase < vc; segbase += DENSE_MAX) {
        uint seglen = min(vc - segbase, (uint)DENSE_MAX);
        for (uint j = t; j < seglen; j += 512) dense[j] = 0ull;
        __syncthreads();                 // also publishes wrank/mask writes
        if (single) {
            for (uint i = lo + t; i < hi; i += 512) {
                u64 rec = recs[i];
                uint cc = (uint)(rec >> 36) & 0x3FFFu;
                uint w = cc >> 5, bit = cc & 31;
                uint r = wrank[w] + __popc(mask[w] & ((1u << bit) - 1u));
                u64 enc = (((rec >> 24) & 0xFFFull) << 46) | (((rec >> 12) & 0xFFFull) << 28)
                        | ((rec & 0xFFFull) << 10) | 1ull;
                atomicAdd(&dense[r], enc);
            }
        } else {
            for (uint i = lo + t; i < hi; i += 512) {
                u64 rec = recs[i];
                uint cc = (uint)(rec >> 36) & 0x3FFFu;
                uint w = cc >> 5, bit = cc & 31;
                uint r = wrank[w] + __popc(mask[w] & ((1u << bit) - 1u));
                if (r >= segbase && r < segbase + seglen) {
                    u64 enc = (((rec >> 24) & 0xFFFull) << 46) | (((rec >> 12) & 0xFFFull) << 28)
                            | ((rec & 0xFFFull) << 10) | 1ull;
                    atomicAdd(&dense[r - segbase], enc);
                }
            }
        }
        __syncthreads();
        // word-parallel emit: thread t owns word t, emits consecutive ranks
        {
            uint mm = mask[t];
            uint r = wrank[t];
            uint kbase = (uint)t << 5;
            while (mm) {
                uint bit = (uint)__ffs(mm) - 1u;
                mm &= mm - 1u;
                if (r >= segbase && r < segbase + seglen) {
                    uint cell = kbase + bit;
                    uint gy = cell >> 7, gz = cell & 127u;
                    u64 p = dense[r - segbase];
                    float cnt = (float)(uint)(p & 1023ull);
                    float inv = 1.0f / fmaxf(cnt, 1.0f);
                    uint uz = (uint)((p >> 10) & 0x3FFFFull);
                    uint uy = (uint)((p >> 28) & 0x3FFFFull);
                    uint ux = (uint)(p >> 46);
                    uint r_out = base_r + r;
                    np_out[3 * r_out + 0] = cx + ((float)ux * QINV) * inv;
                    np_out[3 * r_out + 1] = sy + (float)gy * VS + ((float)uy * QINV) * inv;
                    np_out[3 * r_out + 2] = sz + (float)gz * VS + ((float)uz * QINV) * inv;
                    cnt_out[r_out] = cnt;
                }
                ++r;
            }
        }
        __syncthreads();
    }
}

// ---------------- sparse fallback (G-free keys) ----------------

__device__ __forceinline__ void point_grid(const float* __restrict__ coord, int i,
                                           const int* soff, const float* sstart, int B,
                                           float& x, float& y, float& z,
                                           int& b, int& gx, int& gy, int& gz) {
    x = coord[3 * i + 0]; y = coord[3 * i + 1]; z = coord[3 * i + 2];
    b = 0;
    for (int j = 0; j < B; ++j) b += (i >= soff[j]) ? 1 : 0;
    gx = min((int)floorf((x - sstart[b * 3 + 0]) / VS), 127);
    gy = min((int)floorf((y - sstart[b * 3 + 1]) / VS), 127);
    gz = min((int)floorf((z - sstart[b * 3 + 2]) / VS), 127);
}

__device__ __forceinline__ u64 frac12(float x, float y, float z,
                                      const float* sstart, int b,
                                      int gx, int gy, int gz) {
    float fx = fmaxf(x - (sstart[b * 3 + 0] + (float)gx * VS), 0.0f);
    float fy = fmaxf(y - (sstart[b * 3 + 1] + (float)gy * VS), 0.0f);
    float fz = fmaxf(z - (sstart[b * 3 + 2] + (float)gz * VS), 0.0f);
    uint ux = min((uint)(fx * QSCALE + 0.5f), 4095u);
    uint uy = min((uint)(fy * QSCALE + 0.5f), 4095u);
    uint uz = min((uint)(fz * QSCALE + 0.5f), 4095u);
    return ((u64)ux << 24) | ((u64)uy << 12) | (u64)uz;
}

__global__ void k_hist(const float* __restrict__ coord, const int* __restrict__ offset,
                       int N, int B, const uint* __restrict__ start_m,
                       uint* __restrict__ mask) {
    __shared__ int soff[256];
    __shared__ float sstart[768];
    for (int j = threadIdx.x; j < B; j += blockDim.x) soff[j] = offset[j];
    for (int j = threadIdx.x; j < B * 3; j += blockDim.x) sstart[j] = m2f(start_m[j]);
    __syncthreads();
    int i = blockIdx.x * blockDim.x + threadIdx.x;
    if (i >= N) return;
    float x, y, z; int b, gx, gy, gz;
    point_grid(coord, i, soff, sstart, B, x, y, z, b, gx, gy, gz);
    uint key = ((uint)b << 21) | ((uint)gx << 14) | ((uint)gy << 7) | (uint)gz;
    atomicOr(&mask[key >> 5], 1u << (key & 31));
}

__global__ void k_scan1(const uint* __restrict__ mask, uint* __restrict__ partial) {
    int base = blockIdx.x * 1024 + threadIdx.x * 4;
    uint4 m = *(const uint4*)(mask + base);
    uint s = __popc(m.x) + __popc(m.y) + __popc(m.z) + __popc(m.w);
    for (int d = 32; d; d >>= 1) s += __shfl_xor(s, d);
    __shared__ uint wsum[4];
    if ((threadIdx.x & 63) == 0) wsum[threadIdx.x >> 6] = s;
    __syncthreads();
    if (threadIdx.x == 0) partial[blockIdx.x] = wsum[0] + wsum[1] + wsum[2] + wsum[3];
}

__global__ void k_scan2(uint* partial, int P, uint* total) {
    __shared__ uint t[256];
    uint carry = 0;
    for (int base = 0; base < P; base += 256) {
        int j = base + threadIdx.x;
        uint v = (j < P) ? partial[j] : 0;
        t[threadIdx.x] = v;
        __syncthreads();
        for (int d = 1; d < 256; d <<= 1) {
            uint add = (threadIdx.x >= d) ? t[threadIdx.x - d] : 0;
            __syncthreads();
            t[threadIdx.x] += add;
            __syncthreads();
        }
        uint inc = t[threadIdx.x];
        uint chunk = t[255];
        if (j < P) partial[j] = carry + inc - v;
        __syncthreads();
        carry += chunk;
    }
    if (threadIdx.x == 0) *total = carry;
}

__global__ void k_scan3(const uint* __restrict__ mask, const uint* __restrict__ partial,
                        uint* __restrict__ wordrank) {
    int base = blockIdx.x * 1024 + threadIdx.x * 4;
    uint4 m = *(const uint4*)(mask + base);
    uint c0 = __popc(m.x), c1 = __popc(m.y), c2 = __popc(m.z), c3 = __popc(m.w);
    uint s = c0 + c1 + c2 + c3;
    __shared__ uint t[256];
    t[threadIdx.x] = s;
    __syncthreads();
    for (int d = 1; d < 256; d <<= 1) {
        uint add = (threadIdx.x >= d) ? t[threadIdx.x - d] : 0;
        __syncthreads();
        t[threadIdx.x] += add;
        __syncthreads();
    }
    uint ex = t[threadIdx.x] - s + partial[blockIdx.x];
    uint4 r;
    r.x = ex; r.y = ex + c0; r.z = ex + c0 + c1; r.w = ex + c0 + c1 + c2;
    *(uint4*)(wordrank + base) = r;
}

__global__ void k_no(const uint* mask, const uint* wordrank, const uint* total,
                     float* no_out, int B, int W) {
    int b = blockIdx.x * blockDim.x + threadIdx.x;
    if (b >= B) return;
    long long idx = (long long)(b + 1) << 21;
    uint w = (uint)(idx >> 5);
    uint v;
    if (w >= (uint)W) v = *total;
    else v = wordrank[w];
    no_out[b] = (float)v;
}

__global__ void k_accum_sparse(const float* __restrict__ coord, const int* __restrict__ offset,
                               int N, int B, const uint* __restrict__ start_m,
                               const uint* __restrict__ mask, const uint* __restrict__ wordrank,
                               u64* __restrict__ packed) {
    __shared__ int soff[256];
    __shared__ float sstart[768];
    for (int j = threadIdx.x; j < B; j += blockDim.x) soff[j] = offset[j];
    for (int j = threadIdx.x; j < B * 3; j += blockDim.x) sstart[j] = m2f(start_m[j]);
    __syncthreads();
    int i = blockIdx.x * blockDim.x + threadIdx.x;
    if (i >= N) return;
    float x, y, z; int b, gx, gy, gz;
    point_grid(coord, i, soff, sstart, B, x, y, z, b, gx, gy, gz);
    uint key = ((uint)b << 21) | ((uint)gx << 14) | ((uint)gy << 7) | (uint)gz;
    uint w = key >> 5, bit = key & 31;
    uint r = wordrank[w] + __popc(mask[w] & ((1u << bit) - 1u));
    u64 f = frac12(x, y, z, sstart, b, gx, gy, gz);
    u64 enc = (((f >> 24) & 0xFFFull) << 46) | (((f >> 12) & 0xFFFull) << 28)
            | ((f & 0xFFFull) << 10) | 1ull;
    atomicAdd(&packed[r], enc);
}

__global__ void k_decode_sparse(const uint* __restrict__ mask, const uint* __restrict__ wordrank,
                                const uint* __restrict__ start_m,
                                const u64* __restrict__ packed, int W,
                                float* __restrict__ np_out, float* __restrict__ cnt_out) {
    __shared__ float sstart[48];
    for (int j = threadIdx.x; j < 48; j += blockDim.x) sstart[j] = m2f(start_m[j]);
    __syncthreads();
    int w = blockIdx.x * blockDim.x + threadIdx.x;
    if (w >= W) return;
    uint m = mask[w];
    if (m == 0) return;
    uint r = wordrank[w];
    uint kbase = (uint)w << 5;
    while (m) {
        uint bit = (uint)__ffs(m) - 1u;
        m &= m - 1u;
        uint key = kbase + bit;
        u64 p = packed[r];
        float cnt = (float)(uint)(p & 1023ull);
        float inv = 1.0f / fmaxf(cnt, 1.0f);
        uint uz = (uint)((p >> 10) & 0x3FFFFull);
        uint uy = (uint)((p >> 28) & 0x3FFFFull);
        uint ux = (uint)(p >> 46);
        uint b = key >> 21;
        uint gx = (key >> 14) & 127u;
        uint gy = (key >> 7) & 127u;
        uint gz = key & 127u;
        np_out[3 * r + 0] = sstart[b * 3 + 0] + (float)gx * VS + ((float)ux * QINV) * inv;
        np_out[3 * r + 1] = sstart[b * 3 + 1] + (float)gy * VS + ((float)uy * QINV) * inv;
        np_out[3 * r + 2] = sstart[b * 3 + 2] + (float)gz * VS + ((float)uz * QINV) * inv;
        cnt_out[r] = cnt;
        ++r;
    }
}

extern "C" void kernel_launch(void* const* d_in, const int* in_sizes, int n_in,
                              void* d_out, int out_size, void* d_ws, size_t ws_size,
                              hipStream_t stream) {
    const float* coord = (const float*)d_in[0];
    const int* offset = (const int*)d_in[1];
    int N = in_sizes[0] / 3;
    int B = in_sizes[1];

    float* out = (float*)d_out;
    float* np_out = out;                       // [N,3]
    float* no_out = out + (size_t)3 * N;       // [B]
    float* cnt_out = no_out + B;               // [N]

    uint8_t* base = (uint8_t*)d_ws;
    uint* start_m = (uint*)base;
    uint* total = start_m + (size_t)B * 3;

    // partition-path layout
    uintptr_t p = (uintptr_t)(total + 1);
    p = (p + 255) & ~(uintptr_t)255;
    uint* histm = (uint*)p;          p += (size_t)NBUCKET * NBLK_P * 4;   // 2MB
    p = (p + 255) & ~(uintptr_t)255;
    uint* tot = (uint*)p;            p += (size_t)NBUCKET * 4;
    p = (p + 255) & ~(uintptr_t)255;
    uint* bucket_base = (uint*)p;    p += (size_t)(NBUCKET + 1) * 4;
    p = (p + 255) & ~(uintptr_t)255;
    uint* voxcount = (uint*)p;       p += (size_t)NBUCKET * 4;
    p = (p + 255) & ~(uintptr_t)255;
    uint* voxscan = (uint*)p;        p += (size_t)(NBUCKET + 1) * 4;
    p = (p + 255) & ~(uintptr_t)255;
    uint* gmask = (uint*)p;          p += (size_t)NBUCKET * 512 * 4;      // 4MB
    p = (p + 255) & ~(uintptr_t)255;
    u64* recs = (u64*)p;             p += (size_t)N * 8;                  // 33MB
    p = (p + 255) & ~(uintptr_t)255;
    u64* tmp = (u64*)p;              p += (size_t)N * 8;                  // 33MB
    size_t need_part = p - (uintptr_t)base;

    k_init<<<(B * 3 + 255) / 256, 256, 0, stream>>>(start_m, B * 3);
    k_minmax<<<2048, 256, 0, stream>>>(coord, offset, N, B, start_m);

    if (B <= 16 && ws_size >= need_part) {
        k_count3<<<NBLK_P, 1024, 0, stream>>>(coord, offset, N, B, start_m, histm, tmp);
        k_scanrow<<<NBUCKET, 256, 0, stream>>>(histm, tot);
        k_scan2048<<<1, 1024, 0, stream>>>(tot, bucket_base);
        k_scatter<<<NBLK_P, 1024, 0, stream>>>(tmp, N, histm, bucket_base, recs);
        k_vox<<<NBUCKET, 256, 0, stream>>>(recs, bucket_base, voxcount, gmask);
        k_scan2048b<<<1, 1024, 0, stream>>>(voxcount, voxscan, B, no_out);
        k_emit2<<<NBUCKET + 1024, 512, 0, stream>>>(recs, bucket_base, voxscan, gmask,
                                                    start_m, N, B, out_size,
                                                    np_out, cnt_out, out);
    } else {
        // sparse fallback: G-free 128-stride keys, mask over B*2^21 bits
        hipMemsetAsync(d_out, 0, (size_t)out_size * sizeof(float), stream);
        size_t W = (size_t)B << 16;
        int nblk1 = (int)(W / 1024);
        uintptr_t sp = (uintptr_t)(total + 1);
        sp = (sp + 255) & ~(uintptr_t)255;
        uint* partial = (uint*)sp;   sp += (size_t)nblk1 * 4;
        sp = (sp + 255) & ~(uintptr_t)255;
        uint* mask = (uint*)sp;      sp += W * 4;
        sp = (sp + 255) & ~(uintptr_t)255;
        uint* wordrank = (uint*)sp;  sp += W * 4;
        sp = (sp + 255) & ~(uintptr_t)255;
        u64* packed = (u64*)sp;
        int nb = (N + 255) / 256;
        hipMemsetAsync(mask, 0, W * sizeof(uint), stream);
        hipMemsetAsync(packed, 0, (size_t)N * sizeof(u64), stream);
        k_hist<<<nb, 256, 0, stream>>>(coord, offset, N, B, start_m, mask);
        k_scan1<<<nblk1, 256, 0, stream>>>(mask, partial);
        k_scan2<<<1, 256, 0, stream>>>(partial, nblk1, total);
        k_scan3<<<nblk1, 256, 0, stream>>>(mask, partial, wordrank);
        k_no<<<(B + 63) / 64, 64, 0, stream>>>(mask, wordrank, total, no_out, B, (int)W);
        k_accum_sparse<<<nb, 256, 0, stream>>>(coord, offset, N, B, start_m, mask,
                                               wordrank, packed);
        k_decode_sparse<<<(int)((W + 255) / 256), 256, 0, stream>>>(mask, wordrank, start_m,
                                                                    packed, (int)W,
                                                                    np_out, cnt_out);
    }
}

// Round 9
// 201.319 us; speedup vs baseline: 1.1818x; 1.1818x over previous
//
#include <hip/hip_runtime.h>
#include <stdint.h>

// VSampling R18: revert R17's word-parallel emit (doubled emit to 80us:
// serial bit-walk divergence + uncoalesced output; binary search was FINE --
// TLP hides dependent-LDS latency, not serial divergence). emit2 = R15 exact
// (1024 thr, DENSE_MAX 8192, rank-parallel binary-search emit).
// NEW: both 1-block scan dispatches removed (9 -> 7 launches). Each was a
// full-GPU serialization bubble. k_scatter scans tot in-block (shfl, ~0.2us
// amortized); k_vox / k_emit2 reduce tot/voxcount in-block for lo/hi/base_r;
// emit block 0 writes n_o; tailzero blocks reduce voxcount for total.
// HW rules (measured): per-point global atomics = poison (R11/R13);
// wide-grid __threadfence = poison (R14); LDS atomics fine; rank-parallel
// coalesced emit > owner-parallel bit-walk (R17).
// Keys bit-exact vs ref: IEEE fp32 (c - s)/0.05f + floorf (no fast-math).

typedef unsigned int uint;
typedef unsigned long long u64;

#define VS 0.05f
#define QSCALE (4096.0f / VS)
#define QINV  (VS / 4096.0f)
#define NBUCKET 2048          // B(<=16) * 128
#define NBLK_P 256
#define DENSE_MAX 8192        // emit rank-segment size (64KB LDS)

__device__ __forceinline__ uint f2m(float f) {
    uint b = __float_as_uint(f);
    return (b & 0x80000000u) ? ~b : (b | 0x80000000u);
}
__device__ __forceinline__ float m2f(uint m) {
    uint b = (m & 0x80000000u) ? (m & 0x7fffffffu) : ~m;
    return __uint_as_float(b);
}

__global__ void k_init(uint* start_m, int B3) {
    int i = blockIdx.x * blockDim.x + threadIdx.x;
    if (i < B3) start_m[i] = 0xFFFFFFFFu;
}

// per-batch MIN of each coord axis (R10 version, measured-good).
__global__ void __launch_bounds__(256)
k_minmax(const float* __restrict__ coord, const int* __restrict__ offset,
         int N, int B, uint* start_m) {
    __shared__ uint smin[768];
    __shared__ int soff[256];
    int t = threadIdx.x;
    int nb3 = B * 3;
    for (int j = t; j < B; j += 256) soff[j] = offset[j];
    for (int j = t; j < nb3; j += 256) smin[j] = 0xFFFFFFFFu;
    __syncthreads();

    int F = 3 * N;
    int NQ = F >> 2;
    int per = (NQ + gridDim.x - 1) / gridDim.x;
    int qlo = blockIdx.x * per;
    int qhi = min(NQ, qlo + per);
    const float4* __restrict__ c4 = reinterpret_cast<const float4*>(coord);

    bool fast = false;
    int bU = 0;
    if (qlo < qhi) {
        int pF = (4 * qlo) / 3;
        int pL = (4 * qhi - 1) / 3;
        int bF = 0, bL = 0;
        for (int j = 0; j < B; ++j) {
            bF += (pF >= soff[j]) ? 1 : 0;
            bL += (pL >= soff[j]) ? 1 : 0;
        }
        fast = (bF == bL);
        bU = bF;
    }

    if (fast) {
        int q = qlo + t;
        int p0 = q % 3;
        float s0 = INFINITY, s1 = INFINITY, s2 = INFINITY;
        for (;;) {
            if (q >= qhi) break;
            float4 v = c4[q];
            s0 = fminf(s0, fminf(v.x, v.w)); s1 = fminf(s1, v.y); s2 = fminf(s2, v.z);
            q += 256;
            if (q >= qhi) break;
            v = c4[q];
            s1 = fminf(s1, fminf(v.x, v.w)); s2 = fminf(s2, v.y); s0 = fminf(s0, v.z);
            q += 256;
            if (q >= qhi) break;
            v = c4[q];
            s2 = fminf(s2, fminf(v.x, v.w)); s0 = fminf(s0, v.y); s1 = fminf(s1, v.z);
            q += 256;
        }
        float ax, ay, az;
        if (p0 == 0)      { ax = s0; ay = s1; az = s2; }
        else if (p0 == 1) { ax = s2; ay = s0; az = s1; }
        else              { ax = s1; ay = s2; az = s0; }
        for (int d = 32; d; d >>= 1) {
            ax = fminf(ax, __shfl_xor(ax, d));
            ay = fminf(ay, __shfl_xor(ay, d));
            az = fminf(az, __shfl_xor(az, d));
        }
        if ((t & 63) == 0 && ax < INFINITY) {
            atomicMin(&smin[bU * 3 + 0], f2m(ax));
            atomicMin(&smin[bU * 3 + 1], f2m(ay));
            atomicMin(&smin[bU * 3 + 2], f2m(az));
        }
    } else {
        for (int q = qlo + t; q < qhi; q += 256) {
            float4 v = c4[q];
            int e = 4 * q;
            float vals[4] = {v.x, v.y, v.z, v.w};
#pragma unroll
            for (int k = 0; k < 4; ++k) {
                int ee = e + k;
                int pt = ee / 3;
                int axis = ee - 3 * pt;
                int b = 0;
                for (int j = 0; j < B; ++j) b += (pt >= soff[j]) ? 1 : 0;
                atomicMin(&smin[b * 3 + axis], f2m(vals[k]));
            }
        }
    }

    if (blockIdx.x == 0) {
        for (int ee = 4 * NQ + t; ee < F; ee += 256) {
            int pt = ee / 3;
            int axis = ee - 3 * pt;
            int b = 0;
            for (int j = 0; j < B; ++j) b += (pt >= soff[j]) ? 1 : 0;
            atomicMin(&smin[b * 3 + axis], f2m(coord[ee]));
        }
    }
    __syncthreads();
    for (int j = t; j < nb3; j += 256) {
        uint mn = smin[j];
        if (mn != 0xFFFFFFFFu) atomicMin(&start_m[j], mn);
    }
}

// ---------------- partition pipeline ----------------

// full record for one point: [q:11 | cell:14 | ux:12 | uy:12 | uz:12]
__device__ __forceinline__ u64 mk_rec(float x, float y, float z,
                                      float sx, float sy, float sz,
                                      int b, uint& q) {
    int gx = min((int)floorf((x - sx) / VS), 127);
    int gy = min((int)floorf((y - sy) / VS), 127);
    int gz = min((int)floorf((z - sz) / VS), 127);
    float fx = fmaxf(x - (sx + (float)gx * VS), 0.0f);
    float fy = fmaxf(y - (sy + (float)gy * VS), 0.0f);
    float fz = fmaxf(z - (sz + (float)gz * VS), 0.0f);
    uint ux = min((uint)(fx * QSCALE + 0.5f), 4095u);
    uint uy = min((uint)(fy * QSCALE + 0.5f), 4095u);
    uint uz = min((uint)(fz * QSCALE + 0.5f), 4095u);
    uint cell = ((uint)gy << 7) | (uint)gz;
    q = ((uint)b << 7) | (uint)gx;
    return ((u64)q << 50) | ((u64)cell << 36) | ((u64)ux << 24) | ((u64)uy << 12) | (u64)uz;
}

__device__ __forceinline__ void count_point(float x, float y, float z, int b,
                                            float sx, float sy, float sz, int pid,
                                            uint* hist, u64* __restrict__ tmp) {
    uint q;
    u64 rec = mk_rec(x, y, z, sx, sy, sz, b, q);
    atomicAdd(&hist[q], 1u);        // LDS atomic only
    tmp[pid] = rec;                 // coalesced
}

// per-block LDS histogram -> TRANSPOSED histm[bucket][block]; writes tagged
// records coalesced to tmp. No global atomics.
__global__ void __launch_bounds__(1024)
k_count3(const float* __restrict__ coord, const int* __restrict__ offset,
         int N, int B, const uint* __restrict__ start_m, uint* __restrict__ histm,
         u64* __restrict__ tmp) {
    __shared__ uint hist[NBUCKET];
    __shared__ int soff[16];
    __shared__ float sstart[48];
    int t = threadIdx.x;
    if (t < B) soff[t] = offset[t];
    if (t < B * 3) sstart[t] = m2f(start_m[t]);
    for (int j = t; j < NBUCKET; j += 1024) hist[j] = 0;
    __syncthreads();
    int chunk = (N + gridDim.x - 1) / gridDim.x;
    int lo = blockIdx.x * chunk, hi = min(N, lo + chunk);
    int bLo = 0, bHi = 0;
    for (int j = 0; j < B; ++j) {
        bLo += (lo >= soff[j]) ? 1 : 0;
        bHi += (hi - 1 >= soff[j]) ? 1 : 0;
    }
    if (lo < hi && bLo == bHi && (lo & 3) == 0) {
        int b = bLo;
        float sx = sstart[b * 3 + 0], sy = sstart[b * 3 + 1], sz = sstart[b * 3 + 2];
        const float4* __restrict__ c4 = reinterpret_cast<const float4*>(coord);
        int gEnd = hi >> 2;
        for (int g = (lo >> 2) + t; g < gEnd; g += 1024) {
            float4 v0 = c4[3 * g], v1 = c4[3 * g + 1], v2 = c4[3 * g + 2];
            int p = 4 * g;
            count_point(v0.x, v0.y, v0.z, b, sx, sy, sz, p + 0, hist, tmp);
            count_point(v0.w, v1.x, v1.y, b, sx, sy, sz, p + 1, hist, tmp);
            count_point(v1.z, v1.w, v2.x, b, sx, sy, sz, p + 2, hist, tmp);
            count_point(v2.y, v2.z, v2.w, b, sx, sy, sz, p + 3, hist, tmp);
        }
        for (int i = (gEnd << 2) + t; i < hi; i += 1024) {
            float x = coord[3 * i + 0], y = coord[3 * i + 1], z = coord[3 * i + 2];
            count_point(x, y, z, b, sx, sy, sz, i, hist, tmp);
        }
    } else {
        for (int i = lo + t; i < hi; i += 1024) {
            float x = coord[3 * i + 0], y = coord[3 * i + 1], z = coord[3 * i + 2];
            int b = 0;
            for (int j = 0; j < B; ++j) b += (i >= soff[j]) ? 1 : 0;
            count_point(x, y, z, b, sstart[b * 3 + 0], sstart[b * 3 + 1],
                        sstart[b * 3 + 2], i, hist, tmp);
        }
    }
    __syncthreads();
    for (int j = t; j < NBUCKET; j += 1024)
        histm[(size_t)j * NBLK_P + blockIdx.x] = hist[j];
}

// per-bucket row scan (256 values): exclusive prefix in place + row total.
// shfl wave scan: 2 barriers.
__global__ void __launch_bounds__(256)
k_scanrow(uint* __restrict__ histm, uint* __restrict__ tot) {
    __shared__ uint wtot[4], woff[4];
    uint* row = histm + (size_t)blockIdx.x * NBLK_P;
    int t = threadIdx.x;
    uint v = row[t];
    uint sc = v;
    for (int d = 1; d < 64; d <<= 1) {
        uint nb = __shfl_up(sc, d, 64);
        if ((t & 63) >= d) sc += nb;
    }
    if ((t & 63) == 63) wtot[t >> 6] = sc;
    __syncthreads();
    if (t == 0) {
        uint r = 0;
#pragma unroll
        for (int k = 0; k < 4; ++k) { woff[k] = r; r += wtot[k]; }
    }
    __syncthreads();
    uint incl = sc + woff[t >> 6];
    row[t] = incl - v;
    if (t == 255) tot[blockIdx.x] = incl;
}

// scatter tagged records from tmp (L2/L3-resident) to bucket-grouped recs.
// bucket_base computed IN-BLOCK from tot (shfl scan) -- no scan dispatch.
__global__ void __launch_bounds__(1024)
k_scatter(const u64* __restrict__ tmp, int N,
          const uint* __restrict__ histm, const uint* __restrict__ tot,
          u64* __restrict__ recs) {
    __shared__ uint cursor[NBUCKET];
    __shared__ uint wtot[16], woff[16];
    int t = threadIdx.x;
    uint a = tot[2 * t], bb = tot[2 * t + 1];
    uint s = a + bb, sc = s;
    for (int d = 1; d < 64; d <<= 1) {
        uint nb = __shfl_up(sc, d, 64);
        if ((t & 63) >= d) sc += nb;
    }
    if ((t & 63) == 63) wtot[t >> 6] = sc;
    __syncthreads();
    if (t == 0) {
        uint r = 0;
#pragma unroll
        for (int k = 0; k < 16; ++k) { woff[k] = r; r += wtot[k]; }
    }
    __syncthreads();
    uint incl = sc + woff[t >> 6];
    uint ex = incl - s;
    cursor[2 * t] = ex + histm[(size_t)(2 * t) * NBLK_P + blockIdx.x];
    cursor[2 * t + 1] = ex + a + histm[(size_t)(2 * t + 1) * NBLK_P + blockIdx.x];
    __syncthreads();
    int chunk = (N + gridDim.x - 1) / gridDim.x;
    int lo = blockIdx.x * chunk, hi = min(N, lo + chunk);
    for (int i = lo + t; i < hi; i += 1024) {
        u64 r = tmp[i];
        uint q = (uint)(r >> 50);
        uint slot = atomicAdd(&cursor[q], 1u);   // LDS atomic only
        recs[slot] = r;
    }
}

// per-bucket occupancy: voxcount + store mask to global (recs read = L3 hit).
// lo/hi computed IN-BLOCK by reducing tot[0..q) -- no bucket_base buffer.
__global__ void __launch_bounds__(256)
k_vox(const u64* __restrict__ recs, const uint* __restrict__ tot,
      uint* __restrict__ voxcount, uint* __restrict__ gmask) {
    __shared__ uint bits[512];
    __shared__ uint wsum[4];
    __shared__ uint shlo;
    int q = blockIdx.x;
    int t = threadIdx.x;
    uint s1 = 0;
    for (int j = t; j < q; j += 256) s1 += tot[j];
    for (int d = 32; d; d >>= 1) s1 += __shfl_xor(s1, d);
    if ((t & 63) == 0) wsum[t >> 6] = s1;
    bits[t] = 0;
    bits[t + 256] = 0;
    __syncthreads();
    if (t == 0) shlo = wsum[0] + wsum[1] + wsum[2] + wsum[3];
    __syncthreads();
    uint lo = shlo, hi = lo + tot[q];
    for (uint i = lo + t; i < hi; i += 256) {
        uint c = (uint)(recs[i] >> 36) & 0x3FFFu;
        atomicOr(&bits[c >> 5], 1u << (c & 31));   // LDS atomic only
    }
    __syncthreads();
    uint m0 = bits[t], m1 = bits[t + 256];
    gmask[(size_t)q * 512 + t] = m0;
    gmask[(size_t)q * 512 + t + 256] = m1;
    uint s = __popc(m0) + __popc(m1);
    for (int d = 32; d; d >>= 1) s += __shfl_xor(s, d);
    if ((t & 63) == 0) wsum[t >> 6] = s;
    __syncthreads();
    if (t == 0) voxcount[q] = wsum[0] + wsum[1] + wsum[2] + wsum[3];
}

// rank-dense emit (blocks < NBUCKET) + fused output-tail zeroing (blocks >=
// NBUCKET). R15 emit body (1024 thr, rank-parallel binary-search, coalesced
// output). lo/hi/base_r via in-block reductions; block 0 writes n_o;
// tailzero blocks reduce voxcount for total.
__global__ void __launch_bounds__(1024)
k_emit2(const u64* __restrict__ recs, const uint* __restrict__ tot,
        const uint* __restrict__ voxcount, const uint* __restrict__ gmask,
        const uint* __restrict__ start_m, int N, int B, int out_total,
        float* __restrict__ np_out, float* __restrict__ no_out,
        float* __restrict__ cnt_out, float* __restrict__ out) {
    int t = threadIdx.x;
    if (blockIdx.x >= NBUCKET) {
        __shared__ uint wred[16];
        __shared__ uint totsh;
        uint s = 0;
        for (int j = t; j < NBUCKET; j += 1024) s += voxcount[j];
        for (int d = 32; d; d >>= 1) s += __shfl_xor(s, d);
        if ((t & 63) == 0) wred[t >> 6] = s;
        __syncthreads();
        if (t == 0) { uint r = 0; for (int k = 0; k < 16; ++k) r += wred[k]; totsh = r; }
        __syncthreads();
        uint total = totsh;
        int zb = blockIdx.x - NBUCKET;
        int stride = (gridDim.x - NBUCKET) * 1024;
        int tid = zb * 1024 + t;
        for (int j = 3 * (int)total + tid; j < 3 * N; j += stride) np_out[j] = 0.0f;
        for (int j = (int)total + tid; j < N; j += stride) cnt_out[j] = 0.0f;
        for (int j = 4 * N + B + tid; j < out_total; j += stride) out[j] = 0.0f;
        return;
    }
    __shared__ u64 dense[DENSE_MAX];    // 64 KB
    __shared__ uint mask[512], wrank[512];
    __shared__ uint wtot[16], woff[17];
    __shared__ float sstart[48];
    __shared__ uint shlo, shbase;
    int q = blockIdx.x;
    // lo = sum tot[0..q), base_r = sum voxcount[0..q)
    uint s1 = 0, s2 = 0;
    for (int j = t; j < q; j += 1024) { s1 += tot[j]; s2 += voxcount[j]; }
    for (int d = 32; d; d >>= 1) { s1 += __shfl_xor(s1, d); s2 += __shfl_xor(s2, d); }
    if ((t & 63) == 0) { wtot[t >> 6] = s1; woff[t >> 6] = s2; }
    __syncthreads();
    if (t == 0) {
        uint r1 = 0, r2 = 0;
        for (int k = 0; k < 16; ++k) { r1 += wtot[k]; r2 += woff[k]; }
        shlo = r1; shbase = r2;
    }
    __syncthreads();
    uint lo = shlo, hi = lo + tot[q];
    uint base_r = shbase;
    if (q == 0) {
        // n_o[b] = inclusive sum voxcount[0..(b+1)*128) -- pair-sum scan
        uint a = voxcount[2 * t], bb = voxcount[2 * t + 1];
        uint sp = a + bb, scn = sp;
        for (int d = 1; d < 64; d <<= 1) {
            uint nb = __shfl_up(scn, d, 64);
            if ((t & 63) >= d) scn += nb;
        }
        if ((t & 63) == 63) wtot[t >> 6] = scn;
        __syncthreads();
        if (t == 0) { uint r = 0; for (int k = 0; k < 16; ++k) { woff[k] = r; r += wtot[k]; } }
        __syncthreads();
        uint incl = scn + woff[t >> 6];
        int tp = t + 1;
        if ((tp & 63) == 0) {
            int b = (tp >> 6) - 1;
            if (b < B) no_out[b] = (float)incl;
        }
        __syncthreads();
    }
    if (lo == hi) return;
    if (t < 48) sstart[t] = m2f(start_m[t]);
    uint m = 0, c = 0;
    if (t < 512) {
        m = gmask[(size_t)q * 512 + t];
        mask[t] = m;
        c = __popc(m);
    }
    uint sc = c;
    for (int d = 1; d < 64; d <<= 1) {
        uint nb = __shfl_up(sc, d, 64);
        if ((t & 63) >= d) sc += nb;
    }
    if (t < 512 && (t & 63) == 63) wtot[t >> 6] = sc;
    __syncthreads();
    if (t == 0) {
        uint r = 0;
        for (int k = 0; k < 8; ++k) { woff[k] = r; r += wtot[k]; }
        woff[8] = r;
    }
    __syncthreads();
    if (t < 512) wrank[t] = sc - c + woff[t >> 6];   // exclusive word rank
    uint vc = woff[8];
    int b = q >> 7, gx = q & 127;
    float cx = sstart[b * 3 + 0] + (float)gx * VS;
    float sy = sstart[b * 3 + 1], sz = sstart[b * 3 + 2];
    for (uint segbase = 0; segbase < vc; segbase += DENSE_MAX) {
        uint seglen = min(vc - segbase, (uint)DENSE_MAX);
        for (uint j = t; j < seglen; j += 1024) dense[j] = 0ull;
        __syncthreads();                 // also publishes wrank/mask writes
        for (uint i = lo + t; i < hi; i += 1024) {
            u64 rec = recs[i];
            uint cc = (uint)(rec >> 36) & 0x3FFFu;
            uint w = cc >> 5, bit = cc & 31;
            uint r = wrank[w] + __popc(mask[w] & ((1u << bit) - 1u));
            if (r >= segbase && r < segbase + seglen) {
                u64 enc = (((rec >> 24) & 0xFFFull) << 46) | (((rec >> 12) & 0xFFFull) << 28)
                        | ((rec & 0xFFFull) << 10) | 1ull;
                atomicAdd(&dense[r - segbase], enc);
            }
        }
        __syncthreads();
        // rank-parallel coalesced emit (binary search on wrank)
        for (uint rr = segbase + t; rr < segbase + seglen; rr += 1024) {
            uint l2 = 0, h2 = 511;
            while (l2 < h2) {                       // max word w: wrank[w] <= rr
                uint mid = (l2 + h2 + 1) >> 1;
                if (wrank[mid] <= rr) l2 = mid; else h2 = mid - 1;
            }
            uint w = l2;
            uint idx = rr - wrank[w];
            uint mm = mask[w], bit = 0, cp;
            cp = __popc(mm & 0xFFFFu); if (idx >= cp) { idx -= cp; bit += 16; mm >>= 16; }
            cp = __popc(mm & 0xFFu);   if (idx >= cp) { idx -= cp; bit += 8;  mm >>= 8; }
            cp = __popc(mm & 0xFu);    if (idx >= cp) { idx -= cp; bit += 4;  mm >>= 4; }
            cp = __popc(mm & 0x3u);    if (idx >= cp) { idx -= cp; bit += 2;  mm >>= 2; }
            cp = __popc(mm & 0x1u);    if (idx >= cp) { bit += 1; }
            uint cell = (w << 5) + bit;
            uint gy = cell >> 7, gz = cell & 127u;
            u64 p = dense[rr - segbase];
            float cnt = (float)(uint)(p & 1023ull);
            float inv = 1.0f / fmaxf(cnt, 1.0f);
            uint uz = (uint)((p >> 10) & 0x3FFFFull);
            uint uy = (uint)((p >> 28) & 0x3FFFFull);
            uint ux = (uint)(p >> 46);
            uint r_out = base_r + rr;
            np_out[3 * r_out + 0] = cx + ((float)ux * QINV) * inv;
            np_out[3 * r_out + 1] = sy + (float)gy * VS + ((float)uy * QINV) * inv;
            np_out[3 * r_out + 2] = sz + (float)gz * VS + ((float)uz * QINV) * inv;
            cnt_out[r_out] = cnt;
        }
        __syncthreads();
    }
}

// ---------------- sparse fallback (G-free keys) ----------------

__device__ __forceinline__ void point_grid(const float* __restrict__ coord, int i,
                                           const int* soff, const float* sstart, int B,
                                           float& x, float& y, float& z,
                                           int& b, int& gx, int& gy, int& gz) {
    x = coord[3 * i + 0]; y = coord[3 * i + 1]; z = coord[3 * i + 2];
    b = 0;
    for (int j = 0; j < B; ++j) b += (i >= soff[j]) ? 1 : 0;
    gx = min((int)floorf((x - sstart[b * 3 + 0]) / VS), 127);
    gy = min((int)floorf((y - sstart[b * 3 + 1]) / VS), 127);
    gz = min((int)floorf((z - sstart[b * 3 + 2]) / VS), 127);
}

__device__ __forceinline__ u64 frac12(float x, float y, float z,
                                      const float* sstart, int b,
                                      int gx, int gy, int gz) {
    float fx = fmaxf(x - (sstart[b * 3 + 0] + (float)gx * VS), 0.0f);
    float fy = fmaxf(y - (sstart[b * 3 + 1] + (float)gy * VS), 0.0f);
    float fz = fmaxf(z - (sstart[b * 3 + 2] + (float)gz * VS), 0.0f);
    uint ux = min((uint)(fx * QSCALE + 0.5f), 4095u);
    uint uy = min((uint)(fy * QSCALE + 0.5f), 4095u);
    uint uz = min((uint)(fz * QSCALE + 0.5f), 4095u);
    return ((u64)ux << 24) | ((u64)uy << 12) | (u64)uz;
}

__global__ void k_hist(const float* __restrict__ coord, const int* __restrict__ offset,
                       int N, int B, const uint* __restrict__ start_m,
                       uint* __restrict__ mask) {
    __shared__ int soff[256];
    __shared__ float sstart[768];
    for (int j = threadIdx.x; j < B; j += blockDim.x) soff[j] = offset[j];
    for (int j = threadIdx.x; j < B * 3; j += blockDim.x) sstart[j] = m2f(start_m[j]);
    __syncthreads();
    int i = blockIdx.x * blockDim.x + threadIdx.x;
    if (i >= N) return;
    float x, y, z; int b, gx, gy, gz;
    point_grid(coord, i, soff, sstart, B, x, y, z, b, gx, gy, gz);
    uint key = ((uint)b << 21) | ((uint)gx << 14) | ((uint)gy << 7) | (uint)gz;
    atomicOr(&mask[key >> 5], 1u << (key & 31));
}

__global__ void k_scan1(const uint* __restrict__ mask, uint* __restrict__ partial) {
    int base = blockIdx.x * 1024 + threadIdx.x * 4;
    uint4 m = *(const uint4*)(mask + base);
    uint s = __popc(m.x) + __popc(m.y) + __popc(m.z) + __popc(m.w);
    for (int d = 32; d; d >>= 1) s += __shfl_xor(s, d);
    __shared__ uint wsum[4];
    if ((threadIdx.x & 63) == 0) wsum[threadIdx.x >> 6] = s;
    __syncthreads();
    if (threadIdx.x == 0) partial[blockIdx.x] = wsum[0] + wsum[1] + wsum[2] + wsum[3];
}

__global__ void k_scan2(uint* partial, int P, uint* total) {
    __shared__ uint t[256];
    uint carry = 0;
    for (int base = 0; base < P; base += 256) {
        int j = base + threadIdx.x;
        uint v = (j < P) ? partial[j] : 0;
        t[threadIdx.x] = v;
        __syncthreads();
        for (int d = 1; d < 256; d <<= 1) {
            uint add = (threadIdx.x >= d) ? t[threadIdx.x - d] : 0;
            __syncthreads();
            t[threadIdx.x] += add;
            __syncthreads();
        }
        uint inc = t[threadIdx.x];
        uint chunk = t[255];
        if (j < P) partial[j] = carry + inc - v;
        __syncthreads();
        carry += chunk;
    }
    if (threadIdx.x == 0) *total = carry;
}

__global__ void k_scan3(const uint* __restrict__ mask, const uint* __restrict__ partial,
                        uint* __restrict__ wordrank) {
    int base = blockIdx.x * 1024 + threadIdx.x * 4;
    uint4 m = *(const uint4*)(mask + base);
    uint c0 = __popc(m.x), c1 = __popc(m.y), c2 = __popc(m.z), c3 = __popc(m.w);
    uint s = c0 + c1 + c2 + c3;
    __shared__ uint t[256];
    t[threadIdx.x] = s;
    __syncthreads();
    for (int d = 1; d < 256; d <<= 1) {
        uint add = (threadIdx.x >= d) ? t[threadIdx.x - d] : 0;
        __syncthreads();
        t[threadIdx.x] += add;
        __syncthreads();
    }
    uint ex = t[threadIdx.x] - s + partial[blockIdx.x];
    uint4 r;
    r.x = ex; r.y = ex + c0; r.z = ex + c0 + c1; r.w = ex + c0 + c1 + c2;
    *(uint4*)(wordrank + base) = r;
}

__global__ void k_no(const uint* mask, const uint* wordrank, const uint* total,
                     float* no_out, int B, int W) {
    int b = blockIdx.x * blockDim.x + threadIdx.x;
    if (b >= B) return;
    long long idx = (long long)(b + 1) << 21;
    uint w = (uint)(idx >> 5);
    uint v;
    if (w >= (uint)W) v = *total;
    else v = wordrank[w];
    no_out[b] = (float)v;
}

__global__ void k_accum_sparse(const float* __restrict__ coord, const int* __restrict__ offset,
                               int N, int B, const uint* __restrict__ start_m,
                               const uint* __restrict__ mask, const uint* __restrict__ wordrank,
                               u64* __restrict__ packed) {
    __shared__ int soff[256];
    __shared__ float sstart[768];
    for (int j = threadIdx.x; j < B; j += blockDim.x) soff[j] = offset[j];
    for (int j = threadIdx.x; j < B * 3; j += blockDim.x) sstart[j] = m2f(start_m[j]);
    __syncthreads();
    int i = blockIdx.x * blockDim.x + threadIdx.x;
    if (i >= N) return;
    float x, y, z; int b, gx, gy, gz;
    point_grid(coord, i, soff, sstart, B, x, y, z, b, gx, gy, gz);
    uint key = ((uint)b << 21) | ((uint)gx << 14) | ((uint)gy << 7) | (uint)gz;
    uint w = key >> 5, bit = key & 31;
    uint r = wordrank[w] + __popc(mask[w] & ((1u << bit) - 1u));
    u64 f = frac12(x, y, z, sstart, b, gx, gy, gz);
    u64 enc = (((f >> 24) & 0xFFFull) << 46) | (((f >> 12) & 0xFFFull) << 28)
            | ((f & 0xFFFull) << 10) | 1ull;
    atomicAdd(&packed[r], enc);
}

__global__ void k_decode_sparse(const uint* __restrict__ mask, const uint* __restrict__ wordrank,
                                const uint* __restrict__ start_m,
                                const u64* __restrict__ packed, int W,
                                float* __restrict__ np_out, float* __restrict__ cnt_out) {
    __shared__ float sstart[48];
    for (int j = threadIdx.x; j < 48; j += blockDim.x) sstart[j] = m2f(start_m[j]);
    __syncthreads();
    int w = blockIdx.x * blockDim.x + threadIdx.x;
    if (w >= W) return;
    uint m = mask[w];
    if (m == 0) return;
    uint r = wordrank[w];
    uint kbase = (uint)w << 5;
    while (m) {
        uint bit = (uint)__ffs(m) - 1u;
        m &= m - 1u;
        uint key = kbase + bit;
        u64 p = packed[r];
        float cnt = (float)(uint)(p & 1023ull);
        float inv = 1.0f / fmaxf(cnt, 1.0f);
        uint uz = (uint)((p >> 10) & 0x3FFFFull);
        uint uy = (uint)((p >> 28) & 0x3FFFFull);
        uint ux = (uint)(p >> 46);
        uint b = key >> 21;
        uint gx = (key >> 14) & 127u;
        uint gy = (key >> 7) & 127u;
        uint gz = key & 127u;
        np_out[3 * r + 0] = sstart[b * 3 + 0] + (float)gx * VS + ((float)ux * QINV) * inv;
        np_out[3 * r + 1] = sstart[b * 3 + 1] + (float)gy * VS + ((float)uy * QINV) * inv;
        np_out[3 * r + 2] = sstart[b * 3 + 2] + (float)gz * VS + ((float)uz * QINV) * inv;
        cnt_out[r] = cnt;
        ++r;
    }
}

extern "C" void kernel_launch(void* const* d_in, const int* in_sizes, int n_in,
                              void* d_out, int out_size, void* d_ws, size_t ws_size,
                              hipStream_t stream) {
    const float* coord = (const float*)d_in[0];
    const int* offset = (const int*)d_in[1];
    int N = in_sizes[0] / 3;
    int B = in_sizes[1];

    float* out = (float*)d_out;
    float* np_out = out;                       // [N,3]
    float* no_out = out + (size_t)3 * N;       // [B]
    float* cnt_out = no_out + B;               // [N]

    uint8_t* base = (uint8_t*)d_ws;
    uint* start_m = (uint*)base;
    uint* total = start_m + (size_t)B * 3;

    // partition-path layout
    uintptr_t p = (uintptr_t)(total + 1);
    p = (p + 255) & ~(uintptr_t)255;
    uint* histm = (uint*)p;          p += (size_t)NBUCKET * NBLK_P * 4;   // 2MB
    p = (p + 255) & ~(uintptr_t)255;
    uint* tot = (uint*)p;            p += (size_t)NBUCKET * 4;
    p = (p + 255) & ~(uintptr_t)255;
    uint* voxcount = (uint*)p;       p += (size_t)NBUCKET * 4;
    p = (p + 255) & ~(uintptr_t)255;
    uint* gmask = (uint*)p;          p += (size_t)NBUCKET * 512 * 4;      // 4MB
    p = (p + 255) & ~(uintptr_t)255;
    u64* recs = (u64*)p;             p += (size_t)N * 8;                  // 33MB
    p = (p + 255) & ~(uintptr_t)255;
    u64* tmp = (u64*)p;              p += (size_t)N * 8;                  // 33MB
    size_t need_part = p - (uintptr_t)base;

    k_init<<<(B * 3 + 255) / 256, 256, 0, stream>>>(start_m, B * 3);
    k_minmax<<<2048, 256, 0, stream>>>(coord, offset, N, B, start_m);

    if (B <= 16 && ws_size >= need_part) {
        k_count3<<<NBLK_P, 1024, 0, stream>>>(coord, offset, N, B, start_m, histm, tmp);
        k_scanrow<<<NBUCKET, 256, 0, stream>>>(histm, tot);
        k_scatter<<<NBLK_P, 1024, 0, stream>>>(tmp, N, histm, tot, recs);
        k_vox<<<NBUCKET, 256, 0, stream>>>(recs, tot, voxcount, gmask);
        k_emit2<<<NBUCKET + 1024, 1024, 0, stream>>>(recs, tot, voxcount, gmask,
                                                     start_m, N, B, out_size,
                                                     np_out, no_out, cnt_out, out);
    } else {
        // sparse fallback: G-free 128-stride keys, mask over B*2^21 bits
        hipMemsetAsync(d_out, 0, (size_t)out_size * sizeof(float), stream);
        size_t W = (size_t)B << 16;
        int nblk1 = (int)(W / 1024);
        uintptr_t sp = (uintptr_t)(total + 1);
        sp = (sp + 255) & ~(uintptr_t)255;
        uint* partial = (uint*)sp;   sp += (size_t)nblk1 * 4;
        sp = (sp + 255) & ~(uintptr_t)255;
        uint* mask = (uint*)sp;      sp += W * 4;
        sp = (sp + 255) & ~(uintptr_t)255;
        uint* wordrank = (uint*)sp;  sp += W * 4;
        sp = (sp + 255) & ~(uintptr_t)255;
        u64* packed = (u64*)sp;
        int nb = (N + 255) / 256;
        hipMemsetAsync(mask, 0, W * sizeof(uint), stream);
        hipMemsetAsync(packed, 0, (size_t)N * sizeof(u64), stream);
        k_hist<<<nb, 256, 0, stream>>>(coord, offset, N, B, start_m, mask);
        k_scan1<<<nblk1, 256, 0, stream>>>(mask, partial);
        k_scan2<<<1, 256, 0, stream>>>(partial, nblk1, total);
        k_scan3<<<nblk1, 256, 0, stream>>>(mask, partial, wordrank);
        k_no<<<(B + 63) / 64, 64, 0, stream>>>(mask, wordrank, total, no_out, B, (int)W);
        k_accum_sparse<<<nb, 256, 0, stream>>>(coord, offset, N, B, start_m, mask,
                                               wordrank, packed);
        k_decode_sparse<<<(int)((W + 255) / 256), 256, 0, stream>>>(mask, wordrank, start_m,
                                                                    packed, (int)W,
                                                                    np_out, cnt_out);
    }
}

// Round 10
// 195.048 us; speedup vs baseline: 1.2198x; 1.0321x over previous
//
#include <hip/hip_runtime.h>
#include <stdint.h>

// VSampling R19: emit2 hybrid -- rank-parallel coalesced OUTPUT (R18, proven)
// + owner-parallel rank->cell LDS table build (cheap part of R17's walk).
// cellOf[rank]=cell (u16) written during the dense-zero phase; emit loop does
// ONE stride-1 LDS u16 read per rank instead of 9-dependent-read binary
// search + 5-step bit select (R18 profile: 45us, 1.25M bank conflicts).
// DENSE_MAX 8192->4096 (vc~2300/bucket): LDS 70KB -> ~45KB -> 3 blocks/CU.
// Everything else identical to R18 (passed, 201us).
// HW rules (measured): per-point global atomics = poison (R11/R13);
// wide-grid __threadfence = poison (R14); LDS atomics fine; rank-parallel
// coalesced emit > owner-parallel full-emit bit-walk (R17); 1-block scan
// dispatches are ~free (R18).
// Keys bit-exact vs ref: IEEE fp32 (c - s)/0.05f + floorf (no fast-math).

typedef unsigned int uint;
typedef unsigned short u16;
typedef unsigned long long u64;

#define VS 0.05f
#define QSCALE (4096.0f / VS)
#define QINV  (VS / 4096.0f)
#define NBUCKET 2048          // B(<=16) * 128
#define NBLK_P 256
#define DENSE_MAX 4096        // emit rank-segment size (32KB LDS)

__device__ __forceinline__ uint f2m(float f) {
    uint b = __float_as_uint(f);
    return (b & 0x80000000u) ? ~b : (b | 0x80000000u);
}
__device__ __forceinline__ float m2f(uint m) {
    uint b = (m & 0x80000000u) ? (m & 0x7fffffffu) : ~m;
    return __uint_as_float(b);
}

__global__ void k_init(uint* start_m, int B3) {
    int i = blockIdx.x * blockDim.x + threadIdx.x;
    if (i < B3) start_m[i] = 0xFFFFFFFFu;
}

// per-batch MIN of each coord axis (R10 version, measured-good).
__global__ void __launch_bounds__(256)
k_minmax(const float* __restrict__ coord, const int* __restrict__ offset,
         int N, int B, uint* start_m) {
    __shared__ uint smin[768];
    __shared__ int soff[256];
    int t = threadIdx.x;
    int nb3 = B * 3;
    for (int j = t; j < B; j += 256) soff[j] = offset[j];
    for (int j = t; j < nb3; j += 256) smin[j] = 0xFFFFFFFFu;
    __syncthreads();

    int F = 3 * N;
    int NQ = F >> 2;
    int per = (NQ + gridDim.x - 1) / gridDim.x;
    int qlo = blockIdx.x * per;
    int qhi = min(NQ, qlo + per);
    const float4* __restrict__ c4 = reinterpret_cast<const float4*>(coord);

    bool fast = false;
    int bU = 0;
    if (qlo < qhi) {
        int pF = (4 * qlo) / 3;
        int pL = (4 * qhi - 1) / 3;
        int bF = 0, bL = 0;
        for (int j = 0; j < B; ++j) {
            bF += (pF >= soff[j]) ? 1 : 0;
            bL += (pL >= soff[j]) ? 1 : 0;
        }
        fast = (bF == bL);
        bU = bF;
    }

    if (fast) {
        int q = qlo + t;
        int p0 = q % 3;
        float s0 = INFINITY, s1 = INFINITY, s2 = INFINITY;
        for (;;) {
            if (q >= qhi) break;
            float4 v = c4[q];
            s0 = fminf(s0, fminf(v.x, v.w)); s1 = fminf(s1, v.y); s2 = fminf(s2, v.z);
            q += 256;
            if (q >= qhi) break;
            v = c4[q];
            s1 = fminf(s1, fminf(v.x, v.w)); s2 = fminf(s2, v.y); s0 = fminf(s0, v.z);
            q += 256;
            if (q >= qhi) break;
            v = c4[q];
            s2 = fminf(s2, fminf(v.x, v.w)); s0 = fminf(s0, v.y); s1 = fminf(s1, v.z);
            q += 256;
        }
        float ax, ay, az;
        if (p0 == 0)      { ax = s0; ay = s1; az = s2; }
        else if (p0 == 1) { ax = s2; ay = s0; az = s1; }
        else              { ax = s1; ay = s2; az = s0; }
        for (int d = 32; d; d >>= 1) {
            ax = fminf(ax, __shfl_xor(ax, d));
            ay = fminf(ay, __shfl_xor(ay, d));
            az = fminf(az, __shfl_xor(az, d));
        }
        if ((t & 63) == 0 && ax < INFINITY) {
            atomicMin(&smin[bU * 3 + 0], f2m(ax));
            atomicMin(&smin[bU * 3 + 1], f2m(ay));
            atomicMin(&smin[bU * 3 + 2], f2m(az));
        }
    } else {
        for (int q = qlo + t; q < qhi; q += 256) {
            float4 v = c4[q];
            int e = 4 * q;
            float vals[4] = {v.x, v.y, v.z, v.w};
#pragma unroll
            for (int k = 0; k < 4; ++k) {
                int ee = e + k;
                int pt = ee / 3;
                int axis = ee - 3 * pt;
                int b = 0;
                for (int j = 0; j < B; ++j) b += (pt >= soff[j]) ? 1 : 0;
                atomicMin(&smin[b * 3 + axis], f2m(vals[k]));
            }
        }
    }

    if (blockIdx.x == 0) {
        for (int ee = 4 * NQ + t; ee < F; ee += 256) {
            int pt = ee / 3;
            int axis = ee - 3 * pt;
            int b = 0;
            for (int j = 0; j < B; ++j) b += (pt >= soff[j]) ? 1 : 0;
            atomicMin(&smin[b * 3 + axis], f2m(coord[ee]));
        }
    }
    __syncthreads();
    for (int j = t; j < nb3; j += 256) {
        uint mn = smin[j];
        if (mn != 0xFFFFFFFFu) atomicMin(&start_m[j], mn);
    }
}

// ---------------- partition pipeline ----------------

// full record for one point: [q:11 | cell:14 | ux:12 | uy:12 | uz:12]
__device__ __forceinline__ u64 mk_rec(float x, float y, float z,
                                      float sx, float sy, float sz,
                                      int b, uint& q) {
    int gx = min((int)floorf((x - sx) / VS), 127);
    int gy = min((int)floorf((y - sy) / VS), 127);
    int gz = min((int)floorf((z - sz) / VS), 127);
    float fx = fmaxf(x - (sx + (float)gx * VS), 0.0f);
    float fy = fmaxf(y - (sy + (float)gy * VS), 0.0f);
    float fz = fmaxf(z - (sz + (float)gz * VS), 0.0f);
    uint ux = min((uint)(fx * QSCALE + 0.5f), 4095u);
    uint uy = min((uint)(fy * QSCALE + 0.5f), 4095u);
    uint uz = min((uint)(fz * QSCALE + 0.5f), 4095u);
    uint cell = ((uint)gy << 7) | (uint)gz;
    q = ((uint)b << 7) | (uint)gx;
    return ((u64)q << 50) | ((u64)cell << 36) | ((u64)ux << 24) | ((u64)uy << 12) | (u64)uz;
}

__device__ __forceinline__ void count_point(float x, float y, float z, int b,
                                            float sx, float sy, float sz, int pid,
                                            uint* hist, u64* __restrict__ tmp) {
    uint q;
    u64 rec = mk_rec(x, y, z, sx, sy, sz, b, q);
    atomicAdd(&hist[q], 1u);        // LDS atomic only
    tmp[pid] = rec;                 // coalesced
}

// per-block LDS histogram -> TRANSPOSED histm[bucket][block]; writes tagged
// records coalesced to tmp. No global atomics.
__global__ void __launch_bounds__(1024)
k_count3(const float* __restrict__ coord, const int* __restrict__ offset,
         int N, int B, const uint* __restrict__ start_m, uint* __restrict__ histm,
         u64* __restrict__ tmp) {
    __shared__ uint hist[NBUCKET];
    __shared__ int soff[16];
    __shared__ float sstart[48];
    int t = threadIdx.x;
    if (t < B) soff[t] = offset[t];
    if (t < B * 3) sstart[t] = m2f(start_m[t]);
    for (int j = t; j < NBUCKET; j += 1024) hist[j] = 0;
    __syncthreads();
    int chunk = (N + gridDim.x - 1) / gridDim.x;
    int lo = blockIdx.x * chunk, hi = min(N, lo + chunk);
    int bLo = 0, bHi = 0;
    for (int j = 0; j < B; ++j) {
        bLo += (lo >= soff[j]) ? 1 : 0;
        bHi += (hi - 1 >= soff[j]) ? 1 : 0;
    }
    if (lo < hi && bLo == bHi && (lo & 3) == 0) {
        int b = bLo;
        float sx = sstart[b * 3 + 0], sy = sstart[b * 3 + 1], sz = sstart[b * 3 + 2];
        const float4* __restrict__ c4 = reinterpret_cast<const float4*>(coord);
        int gEnd = hi >> 2;
        for (int g = (lo >> 2) + t; g < gEnd; g += 1024) {
            float4 v0 = c4[3 * g], v1 = c4[3 * g + 1], v2 = c4[3 * g + 2];
            int p = 4 * g;
            count_point(v0.x, v0.y, v0.z, b, sx, sy, sz, p + 0, hist, tmp);
            count_point(v0.w, v1.x, v1.y, b, sx, sy, sz, p + 1, hist, tmp);
            count_point(v1.z, v1.w, v2.x, b, sx, sy, sz, p + 2, hist, tmp);
            count_point(v2.y, v2.z, v2.w, b, sx, sy, sz, p + 3, hist, tmp);
        }
        for (int i = (gEnd << 2) + t; i < hi; i += 1024) {
            float x = coord[3 * i + 0], y = coord[3 * i + 1], z = coord[3 * i + 2];
            count_point(x, y, z, b, sx, sy, sz, i, hist, tmp);
        }
    } else {
        for (int i = lo + t; i < hi; i += 1024) {
            float x = coord[3 * i + 0], y = coord[3 * i + 1], z = coord[3 * i + 2];
            int b = 0;
            for (int j = 0; j < B; ++j) b += (i >= soff[j]) ? 1 : 0;
            count_point(x, y, z, b, sstart[b * 3 + 0], sstart[b * 3 + 1],
                        sstart[b * 3 + 2], i, hist, tmp);
        }
    }
    __syncthreads();
    for (int j = t; j < NBUCKET; j += 1024)
        histm[(size_t)j * NBLK_P + blockIdx.x] = hist[j];
}

// per-bucket row scan (256 values): exclusive prefix in place + row total.
// shfl wave scan: 2 barriers.
__global__ void __launch_bounds__(256)
k_scanrow(uint* __restrict__ histm, uint* __restrict__ tot) {
    __shared__ uint wtot[4], woff[4];
    uint* row = histm + (size_t)blockIdx.x * NBLK_P;
    int t = threadIdx.x;
    uint v = row[t];
    uint sc = v;
    for (int d = 1; d < 64; d <<= 1) {
        uint nb = __shfl_up(sc, d, 64);
        if ((t & 63) >= d) sc += nb;
    }
    if ((t & 63) == 63) wtot[t >> 6] = sc;
    __syncthreads();
    if (t == 0) {
        uint r = 0;
#pragma unroll
        for (int k = 0; k < 4; ++k) { woff[k] = r; r += wtot[k]; }
    }
    __syncthreads();
    uint incl = sc + woff[t >> 6];
    row[t] = incl - v;
    if (t == 255) tot[blockIdx.x] = incl;
}

// scatter tagged records from tmp (L2/L3-resident) to bucket-grouped recs.
// bucket_base computed IN-BLOCK from tot (shfl scan) -- no scan dispatch.
__global__ void __launch_bounds__(1024)
k_scatter(const u64* __restrict__ tmp, int N,
          const uint* __restrict__ histm, const uint* __restrict__ tot,
          u64* __restrict__ recs) {
    __shared__ uint cursor[NBUCKET];
    __shared__ uint wtot[16], woff[16];
    int t = threadIdx.x;
    uint a = tot[2 * t], bb = tot[2 * t + 1];
    uint s = a + bb, sc = s;
    for (int d = 1; d < 64; d <<= 1) {
        uint nb = __shfl_up(sc, d, 64);
        if ((t & 63) >= d) sc += nb;
    }
    if ((t & 63) == 63) wtot[t >> 6] = sc;
    __syncthreads();
    if (t == 0) {
        uint r = 0;
#pragma unroll
        for (int k = 0; k < 16; ++k) { woff[k] = r; r += wtot[k]; }
    }
    __syncthreads();
    uint incl = sc + woff[t >> 6];
    uint ex = incl - s;
    cursor[2 * t] = ex + histm[(size_t)(2 * t) * NBLK_P + blockIdx.x];
    cursor[2 * t + 1] = ex + a + histm[(size_t)(2 * t + 1) * NBLK_P + blockIdx.x];
    __syncthreads();
    int chunk = (N + gridDim.x - 1) / gridDim.x;
    int lo = blockIdx.x * chunk, hi = min(N, lo + chunk);
    for (int i = lo + t; i < hi; i += 1024) {
        u64 r = tmp[i];
        uint q = (uint)(r >> 50);
        uint slot = atomicAdd(&cursor[q], 1u);   // LDS atomic only
        recs[slot] = r;
    }
}

// per-bucket occupancy: voxcount + store mask to global (recs read = L3 hit).
// lo/hi computed IN-BLOCK by reducing tot[0..q) -- no bucket_base buffer.
__global__ void __launch_bounds__(256)
k_vox(const u64* __restrict__ recs, const uint* __restrict__ tot,
      uint* __restrict__ voxcount, uint* __restrict__ gmask) {
    __shared__ uint bits[512];
    __shared__ uint wsum[4];
    __shared__ uint shlo;
    int q = blockIdx.x;
    int t = threadIdx.x;
    uint s1 = 0;
    for (int j = t; j < q; j += 256) s1 += tot[j];
    for (int d = 32; d; d >>= 1) s1 += __shfl_xor(s1, d);
    if ((t & 63) == 0) wsum[t >> 6] = s1;
    bits[t] = 0;
    bits[t + 256] = 0;
    __syncthreads();
    if (t == 0) shlo = wsum[0] + wsum[1] + wsum[2] + wsum[3];
    __syncthreads();
    uint lo = shlo, hi = lo + tot[q];
    for (uint i = lo + t; i < hi; i += 256) {
        uint c = (uint)(recs[i] >> 36) & 0x3FFFu;
        atomicOr(&bits[c >> 5], 1u << (c & 31));   // LDS atomic only
    }
    __syncthreads();
    uint m0 = bits[t], m1 = bits[t + 256];
    gmask[(size_t)q * 512 + t] = m0;
    gmask[(size_t)q * 512 + t + 256] = m1;
    uint s = __popc(m0) + __popc(m1);
    for (int d = 32; d; d >>= 1) s += __shfl_xor(s, d);
    if ((t & 63) == 0) wsum[t >> 6] = s;
    __syncthreads();
    if (t == 0) voxcount[q] = wsum[0] + wsum[1] + wsum[2] + wsum[3];
}

// rank-dense emit (blocks < NBUCKET) + fused output-tail zeroing (blocks >=
// NBUCKET). Rank-parallel coalesced emit via precomputed cellOf[rank] (u16)
// built by word-owner bit-walk during the dense-zero phase (1 stride-1 LDS
// read per rank vs 9-read binary search). lo/hi/base_r via in-block
// reductions; block 0 writes n_o; tailzero blocks reduce voxcount for total.
__global__ void __launch_bounds__(1024)
k_emit2(const u64* __restrict__ recs, const uint* __restrict__ tot,
        const uint* __restrict__ voxcount, const uint* __restrict__ gmask,
        const uint* __restrict__ start_m, int N, int B, int out_total,
        float* __restrict__ np_out, float* __restrict__ no_out,
        float* __restrict__ cnt_out, float* __restrict__ out) {
    int t = threadIdx.x;
    if (blockIdx.x >= NBUCKET) {
        __shared__ uint wred[16];
        __shared__ uint totsh;
        uint s = 0;
        for (int j = t; j < NBUCKET; j += 1024) s += voxcount[j];
        for (int d = 32; d; d >>= 1) s += __shfl_xor(s, d);
        if ((t & 63) == 0) wred[t >> 6] = s;
        __syncthreads();
        if (t == 0) { uint r = 0; for (int k = 0; k < 16; ++k) r += wred[k]; totsh = r; }
        __syncthreads();
        uint total = totsh;
        int zb = blockIdx.x - NBUCKET;
        int stride = (gridDim.x - NBUCKET) * 1024;
        int tid = zb * 1024 + t;
        for (int j = 3 * (int)total + tid; j < 3 * N; j += stride) np_out[j] = 0.0f;
        for (int j = (int)total + tid; j < N; j += stride) cnt_out[j] = 0.0f;
        for (int j = 4 * N + B + tid; j < out_total; j += stride) out[j] = 0.0f;
        return;
    }
    __shared__ u64 dense[DENSE_MAX];    // 32 KB
    __shared__ uint mask[512], wrank[512];
    __shared__ u16 cellOf[DENSE_MAX];   // 8 KB
    __shared__ uint wtot[16], woff[17];
    __shared__ float sstart[48];
    __shared__ uint shlo, shbase;
    int q = blockIdx.x;
    // lo = sum tot[0..q), base_r = sum voxcount[0..q)
    uint s1 = 0, s2 = 0;
    for (int j = t; j < q; j += 1024) { s1 += tot[j]; s2 += voxcount[j]; }
    for (int d = 32; d; d >>= 1) { s1 += __shfl_xor(s1, d); s2 += __shfl_xor(s2, d); }
    if ((t & 63) == 0) { wtot[t >> 6] = s1; woff[t >> 6] = s2; }
    __syncthreads();
    if (t == 0) {
        uint r1 = 0, r2 = 0;
        for (int k = 0; k < 16; ++k) { r1 += wtot[k]; r2 += woff[k]; }
        shlo = r1; shbase = r2;
    }
    __syncthreads();
    uint lo = shlo, hi = lo + tot[q];
    uint base_r = shbase;
    if (q == 0) {
        // n_o[b] = inclusive sum voxcount[0..(b+1)*128) -- pair-sum scan
        uint a = voxcount[2 * t], bb = voxcount[2 * t + 1];
        uint sp = a + bb, scn = sp;
        for (int d = 1; d < 64; d <<= 1) {
            uint nb = __shfl_up(scn, d, 64);
            if ((t & 63) >= d) scn += nb;
        }
        if ((t & 63) == 63) wtot[t >> 6] = scn;
        __syncthreads();
        if (t == 0) { uint r = 0; for (int k = 0; k < 16; ++k) { woff[k] = r; r += wtot[k]; } }
        __syncthreads();
        uint incl = scn + woff[t >> 6];
        int tp = t + 1;
        if ((tp & 63) == 0) {
            int b = (tp >> 6) - 1;
            if (b < B) no_out[b] = (float)incl;
        }
        __syncthreads();
    }
    if (lo == hi) return;
    if (t < 48) sstart[t] = m2f(start_m[t]);
    uint m = 0, c = 0;
    if (t < 512) {
        m = gmask[(size_t)q * 512 + t];
        mask[t] = m;
        c = __popc(m);
    }
    uint sc = c;
    for (int d = 1; d < 64; d <<= 1) {
        uint nb = __shfl_up(sc, d, 64);
        if ((t & 63) >= d) sc += nb;
    }
    if (t < 512 && (t & 63) == 63) wtot[t >> 6] = sc;
    __syncthreads();
    if (t == 0) {
        uint r = 0;
        for (int k = 0; k < 8; ++k) { woff[k] = r; r += wtot[k]; }
        woff[8] = r;
    }
    __syncthreads();
    if (t < 512) wrank[t] = sc - c + woff[t >> 6];   // exclusive word rank
    uint vc = woff[8];
    int b = q >> 7, gx = q & 127;
    float cx = sstart[b * 3 + 0] + (float)gx * VS;
    float sy = sstart[b * 3 + 1], sz = sstart[b * 3 + 2];
    for (uint segbase = 0; segbase < vc; segbase += DENSE_MAX) {
        uint seglen = min(vc - segbase, (uint)DENSE_MAX);
        for (uint j = t; j < seglen; j += 1024) dense[j] = 0ull;
        // owner-walk: build cellOf for this segment (u16 LDS writes, disjoint)
        if (t < 512) {
            uint mm = mask[t];
            uint r = wrank[t];
            uint kbase = (uint)t << 5;
            while (mm) {
                uint bit = (uint)__ffs(mm) - 1u;
                mm &= mm - 1u;
                if (r >= segbase && r < segbase + seglen)
                    cellOf[r - segbase] = (u16)(kbase + bit);
                ++r;
            }
        }
        __syncthreads();                 // publishes dense-zero + cellOf + wrank/mask
        for (uint i = lo + t; i < hi; i += 1024) {
            u64 rec = recs[i];
            uint cc = (uint)(rec >> 36) & 0x3FFFu;
            uint w = cc >> 5, bit = cc & 31;
            uint r = wrank[w] + __popc(mask[w] & ((1u << bit) - 1u));
            if (r >= segbase && r < segbase + seglen) {
                u64 enc = (((rec >> 24) & 0xFFFull) << 46) | (((rec >> 12) & 0xFFFull) << 28)
                        | ((rec & 0xFFFull) << 10) | 1ull;
                atomicAdd(&dense[r - segbase], enc);
            }
        }
        __syncthreads();
        // rank-parallel coalesced emit: 1 stride-1 u16 LDS read per rank
        for (uint rr = segbase + t; rr < segbase + seglen; rr += 1024) {
            uint cell = cellOf[rr - segbase];
            uint gy = cell >> 7, gz = cell & 127u;
            u64 p = dense[rr - segbase];
            float cnt = (float)(uint)(p & 1023ull);
            float inv = 1.0f / fmaxf(cnt, 1.0f);
            uint uz = (uint)((p >> 10) & 0x3FFFFull);
            uint uy = (uint)((p >> 28) & 0x3FFFFull);
            uint ux = (uint)(p >> 46);
            uint r_out = base_r + rr;
            np_out[3 * r_out + 0] = cx + ((float)ux * QINV) * inv;
            np_out[3 * r_out + 1] = sy + (float)gy * VS + ((float)uy * QINV) * inv;
            np_out[3 * r_out + 2] = sz + (float)gz * VS + ((float)uz * QINV) * inv;
            cnt_out[r_out] = cnt;
        }
        __syncthreads();
    }
}

// ---------------- sparse fallback (G-free keys) ----------------

__device__ __forceinline__ void point_grid(const float* __restrict__ coord, int i,
                                           const int* soff, const float* sstart, int B,
                                           float& x, float& y, float& z,
                                           int& b, int& gx, int& gy, int& gz) {
    x = coord[3 * i + 0]; y = coord[3 * i + 1]; z = coord[3 * i + 2];
    b = 0;
    for (int j = 0; j < B; ++j) b += (i >= soff[j]) ? 1 : 0;
    gx = min((int)floorf((x - sstart[b * 3 + 0]) / VS), 127);
    gy = min((int)floorf((y - sstart[b * 3 + 1]) / VS), 127);
    gz = min((int)floorf((z - sstart[b * 3 + 2]) / VS), 127);
}

__device__ __forceinline__ u64 frac12(float x, float y, float z,
                                      const float* sstart, int b,
                                      int gx, int gy, int gz) {
    float fx = fmaxf(x - (sstart[b * 3 + 0] + (float)gx * VS), 0.0f);
    float fy = fmaxf(y - (sstart[b * 3 + 1] + (float)gy * VS), 0.0f);
    float fz = fmaxf(z - (sstart[b * 3 + 2] + (float)gz * VS), 0.0f);
    uint ux = min((uint)(fx * QSCALE + 0.5f), 4095u);
    uint uy = min((uint)(fy * QSCALE + 0.5f), 4095u);
    uint uz = min((uint)(fz * QSCALE + 0.5f), 4095u);
    return ((u64)ux << 24) | ((u64)uy << 12) | (u64)uz;
}

__global__ void k_hist(const float* __restrict__ coord, const int* __restrict__ offset,
                       int N, int B, const uint* __restrict__ start_m,
                       uint* __restrict__ mask) {
    __shared__ int soff[256];
    __shared__ float sstart[768];
    for (int j = threadIdx.x; j < B; j += blockDim.x) soff[j] = offset[j];
    for (int j = threadIdx.x; j < B * 3; j += blockDim.x) sstart[j] = m2f(start_m[j]);
    __syncthreads();
    int i = blockIdx.x * blockDim.x + threadIdx.x;
    if (i >= N) return;
    float x, y, z; int b, gx, gy, gz;
    point_grid(coord, i, soff, sstart, B, x, y, z, b, gx, gy, gz);
    uint key = ((uint)b << 21) | ((uint)gx << 14) | ((uint)gy << 7) | (uint)gz;
    atomicOr(&mask[key >> 5], 1u << (key & 31));
}

__global__ void k_scan1(const uint* __restrict__ mask, uint* __restrict__ partial) {
    int base = blockIdx.x * 1024 + threadIdx.x * 4;
    uint4 m = *(const uint4*)(mask + base);
    uint s = __popc(m.x) + __popc(m.y) + __popc(m.z) + __popc(m.w);
    for (int d = 32; d; d >>= 1) s += __shfl_xor(s, d);
    __shared__ uint wsum[4];
    if ((threadIdx.x & 63) == 0) wsum[threadIdx.x >> 6] = s;
    __syncthreads();
    if (threadIdx.x == 0) partial[blockIdx.x] = wsum[0] + wsum[1] + wsum[2] + wsum[3];
}

__global__ void k_scan2(uint* partial, int P, uint* total) {
    __shared__ uint t[256];
    uint carry = 0;
    for (int base = 0; base < P; base += 256) {
        int j = base + threadIdx.x;
        uint v = (j < P) ? partial[j] : 0;
        t[threadIdx.x] = v;
        __syncthreads();
        for (int d = 1; d < 256; d <<= 1) {
            uint add = (threadIdx.x >= d) ? t[threadIdx.x - d] : 0;
            __syncthreads();
            t[threadIdx.x] += add;
            __syncthreads();
        }
        uint inc = t[threadIdx.x];
        uint chunk = t[255];
        if (j < P) partial[j] = carry + inc - v;
        __syncthreads();
        carry += chunk;
    }
    if (threadIdx.x == 0) *total = carry;
}

__global__ void k_scan3(const uint* __restrict__ mask, const uint* __restrict__ partial,
                        uint* __restrict__ wordrank) {
    int base = blockIdx.x * 1024 + threadIdx.x * 4;
    uint4 m = *(const uint4*)(mask + base);
    uint c0 = __popc(m.x), c1 = __popc(m.y), c2 = __popc(m.z), c3 = __popc(m.w);
    uint s = c0 + c1 + c2 + c3;
    __shared__ uint t[256];
    t[threadIdx.x] = s;
    __syncthreads();
    for (int d = 1; d < 256; d <<= 1) {
        uint add = (threadIdx.x >= d) ? t[threadIdx.x - d] : 0;
        __syncthreads();
        t[threadIdx.x] += add;
        __syncthreads();
    }
    uint ex = t[threadIdx.x] - s + partial[blockIdx.x];
    uint4 r;
    r.x = ex; r.y = ex + c0; r.z = ex + c0 + c1; r.w = ex + c0 + c1 + c2;
    *(uint4*)(wordrank + base) = r;
}

__global__ void k_no(const uint* mask, const uint* wordrank, const uint* total,
                     float* no_out, int B, int W) {
    int b = blockIdx.x * blockDim.x + threadIdx.x;
    if (b >= B) return;
    long long idx = (long long)(b + 1) << 21;
    uint w = (uint)(idx >> 5);
    uint v;
    if (w >= (uint)W) v = *total;
    else v = wordrank[w];
    no_out[b] = (float)v;
}

__global__ void k_accum_sparse(const float* __restrict__ coord, const int* __restrict__ offset,
                               int N, int B, const uint* __restrict__ start_m,
                               const uint* __restrict__ mask, const uint* __restrict__ wordrank,
                               u64* __restrict__ packed) {
    __shared__ int soff[256];
    __shared__ float sstart[768];
    for (int j = threadIdx.x; j < B; j += blockDim.x) soff[j] = offset[j];
    for (int j = threadIdx.x; j < B * 3; j += blockDim.x) sstart[j] = m2f(start_m[j]);
    __syncthreads();
    int i = blockIdx.x * blockDim.x + threadIdx.x;
    if (i >= N) return;
    float x, y, z; int b, gx, gy, gz;
    point_grid(coord, i, soff, sstart, B, x, y, z, b, gx, gy, gz);
    uint key = ((uint)b << 21) | ((uint)gx << 14) | ((uint)gy << 7) | (uint)gz;
    uint w = key >> 5, bit = key & 31;
    uint r = wordrank[w] + __popc(mask[w] & ((1u << bit) - 1u));
    u64 f = frac12(x, y, z, sstart, b, gx, gy, gz);
    u64 enc = (((f >> 24) & 0xFFFull) << 46) | (((f >> 12) & 0xFFFull) << 28)
            | ((f & 0xFFFull) << 10) | 1ull;
    atomicAdd(&packed[r], enc);
}

__global__ void k_decode_sparse(const uint* __restrict__ mask, const uint* __restrict__ wordrank,
                                const uint* __restrict__ start_m,
                                const u64* __restrict__ packed, int W,
                                float* __restrict__ np_out, float* __restrict__ cnt_out) {
    __shared__ float sstart[48];
    for (int j = threadIdx.x; j < 48; j += blockDim.x) sstart[j] = m2f(start_m[j]);
    __syncthreads();
    int w = blockIdx.x * blockDim.x + threadIdx.x;
    if (w >= W) return;
    uint m = mask[w];
    if (m == 0) return;
    uint r = wordrank[w];
    uint kbase = (uint)w << 5;
    while (m) {
        uint bit = (uint)__ffs(m) - 1u;
        m &= m - 1u;
        uint key = kbase + bit;
        u64 p = packed[r];
        float cnt = (float)(uint)(p & 1023ull);
        float inv = 1.0f / fmaxf(cnt, 1.0f);
        uint uz = (uint)((p >> 10) & 0x3FFFFull);
        uint uy = (uint)((p >> 28) & 0x3FFFFull);
        uint ux = (uint)(p >> 46);
        uint b = key >> 21;
        uint gx = (key >> 14) & 127u;
        uint gy = (key >> 7) & 127u;
        uint gz = key & 127u;
        np_out[3 * r + 0] = sstart[b * 3 + 0] + (float)gx * VS + ((float)ux * QINV) * inv;
        np_out[3 * r + 1] = sstart[b * 3 + 1] + (float)gy * VS + ((float)uy * QINV) * inv;
        np_out[3 * r + 2] = sstart[b * 3 + 2] + (float)gz * VS + ((float)uz * QINV) * inv;
        cnt_out[r] = cnt;
        ++r;
    }
}

extern "C" void kernel_launch(void* const* d_in, const int* in_sizes, int n_in,
                              void* d_out, int out_size, void* d_ws, size_t ws_size,
                              hipStream_t stream) {
    const float* coord = (const float*)d_in[0];
    const int* offset = (const int*)d_in[1];
    int N = in_sizes[0] / 3;
    int B = in_sizes[1];

    float* out = (float*)d_out;
    float* np_out = out;                       // [N,3]
    float* no_out = out + (size_t)3 * N;       // [B]
    float* cnt_out = no_out + B;               // [N]

    uint8_t* base = (uint8_t*)d_ws;
    uint* start_m = (uint*)base;
    uint* total = start_m + (size_t)B * 3;

    // partition-path layout
    uintptr_t p = (uintptr_t)(total + 1);
    p = (p + 255) & ~(uintptr_t)255;
    uint* histm = (uint*)p;          p += (size_t)NBUCKET * NBLK_P * 4;   // 2MB
    p = (p + 255) & ~(uintptr_t)255;
    uint* tot = (uint*)p;            p += (size_t)NBUCKET * 4;
    p = (p + 255) & ~(uintptr_t)255;
    uint* voxcount = (uint*)p;       p += (size_t)NBUCKET * 4;
    p = (p + 255) & ~(uintptr_t)255;
    uint* gmask = (uint*)p;          p += (size_t)NBUCKET * 512 * 4;      // 4MB
    p = (p + 255) & ~(uintptr_t)255;
    u64* recs = (u64*)p;             p += (size_t)N * 8;                  // 33MB
    p = (p + 255) & ~(uintptr_t)255;
    u64* tmp = (u64*)p;              p += (size_t)N * 8;                  // 33MB
    size_t need_part = p - (uintptr_t)base;

    k_init<<<(B * 3 + 255) / 256, 256, 0, stream>>>(start_m, B * 3);
    k_minmax<<<2048, 256, 0, stream>>>(coord, offset, N, B, start_m);

    if (B <= 16 && ws_size >= need_part) {
        k_count3<<<NBLK_P, 1024, 0, stream>>>(coord, offset, N, B, start_m, histm, tmp);
        k_scanrow<<<NBUCKET, 256, 0, stream>>>(histm, tot);
        k_scatter<<<NBLK_P, 1024, 0, stream>>>(tmp, N, histm, tot, recs);
        k_vox<<<NBUCKET, 256, 0, stream>>>(recs, tot, voxcount, gmask);
        k_emit2<<<NBUCKET + 1024, 1024, 0, stream>>>(recs, tot, voxcount, gmask,
                                                     start_m, N, B, out_size,
                                                     np_out, no_out, cnt_out, out);
    } else {
        // sparse fallback: G-free 128-stride keys, mask over B*2^21 bits
        hipMemsetAsync(d_out, 0, (size_t)out_size * sizeof(float), stream);
        size_t W = (size_t)B << 16;
        int nblk1 = (int)(W / 1024);
        uintptr_t sp = (uintptr_t)(total + 1);
        sp = (sp + 255) & ~(uintptr_t)255;
        uint* partial = (uint*)sp;   sp += (size_t)nblk1 * 4;
        sp = (sp + 255) & ~(uintptr_t)255;
        uint* mask = (uint*)sp;      sp += W * 4;
        sp = (sp + 255) & ~(uintptr_t)255;
        uint* wordrank = (uint*)sp;  sp += W * 4;
        sp = (sp + 255) & ~(uintptr_t)255;
        u64* packed = (u64*)sp;
        int nb = (N + 255) / 256;
        hipMemsetAsync(mask, 0, W * sizeof(uint), stream);
        hipMemsetAsync(packed, 0, (size_t)N * sizeof(u64), stream);
        k_hist<<<nb, 256, 0, stream>>>(coord, offset, N, B, start_m, mask);
        k_scan1<<<nblk1, 256, 0, stream>>>(mask, partial);
        k_scan2<<<1, 256, 0, stream>>>(partial, nblk1, total);
        k_scan3<<<nblk1, 256, 0, stream>>>(mask, partial, wordrank);
        k_no<<<(B + 63) / 64, 64, 0, stream>>>(mask, wordrank, total, no_out, B, (int)W);
        k_accum_sparse<<<nb, 256, 0, stream>>>(coord, offset, N, B, start_m, mask,
                                               wordrank, packed);
        k_decode_sparse<<<(int)((W + 255) / 256), 256, 0, stream>>>(mask, wordrank, start_m,
                                                                    packed, (int)W,
                                                                    np_out, cnt_out);
    }
}

// Round 11
// 193.705 us; speedup vs baseline: 1.2282x; 1.0069x over previous
//
#include <hip/hip_runtime.h>
#include <stdint.h>

// VSampling R20: R15 launch skeleton + R19's cellOf emit. R19 post-mortem:
// emit2's 42us is per-block FIXED cost x 3072 blocks -- the R18 in-block
// prefix reductions (2 latency-bound global loops over tot/voxcount + extra
// barriers per block) dominate; marginal record/rank work is ~noise. R18
// proved 1-block scan dispatches are ~free, so restore them and strip the
// in-block reductions everywhere. Conflicts (1.4M) are from dense u64 LDS
// atomics, NOT the search (R19 falsified that).
// HW rules (measured): per-point global atomics = poison (R11/R13);
// wide-grid __threadfence = poison (R14); LDS atomics fine; rank-parallel
// coalesced emit > owner-parallel full-emit bit-walk (R17); 1-block scans
// ~free (R18); per-block global-reduction fixed cost is the emit killer (R19).
// Keys bit-exact vs ref: IEEE fp32 (c - s)/0.05f + floorf (no fast-math).

typedef unsigned int uint;
typedef unsigned short u16;
typedef unsigned long long u64;

#define VS 0.05f
#define QSCALE (4096.0f / VS)
#define QINV  (VS / 4096.0f)
#define NBUCKET 2048          // B(<=16) * 128
#define NBLK_P 256
#define DENSE_MAX 4096        // emit rank-segment size (32KB LDS)

__device__ __forceinline__ uint f2m(float f) {
    uint b = __float_as_uint(f);
    return (b & 0x80000000u) ? ~b : (b | 0x80000000u);
}
__device__ __forceinline__ float m2f(uint m) {
    uint b = (m & 0x80000000u) ? (m & 0x7fffffffu) : ~m;
    return __uint_as_float(b);
}

__global__ void k_init(uint* start_m, int B3) {
    int i = blockIdx.x * blockDim.x + threadIdx.x;
    if (i < B3) start_m[i] = 0xFFFFFFFFu;
}

// per-batch MIN of each coord axis (R10 version, measured-good).
__global__ void __launch_bounds__(256)
k_minmax(const float* __restrict__ coord, const int* __restrict__ offset,
         int N, int B, uint* start_m) {
    __shared__ uint smin[768];
    __shared__ int soff[256];
    int t = threadIdx.x;
    int nb3 = B * 3;
    for (int j = t; j < B; j += 256) soff[j] = offset[j];
    for (int j = t; j < nb3; j += 256) smin[j] = 0xFFFFFFFFu;
    __syncthreads();

    int F = 3 * N;
    int NQ = F >> 2;
    int per = (NQ + gridDim.x - 1) / gridDim.x;
    int qlo = blockIdx.x * per;
    int qhi = min(NQ, qlo + per);
    const float4* __restrict__ c4 = reinterpret_cast<const float4*>(coord);

    bool fast = false;
    int bU = 0;
    if (qlo < qhi) {
        int pF = (4 * qlo) / 3;
        int pL = (4 * qhi - 1) / 3;
        int bF = 0, bL = 0;
        for (int j = 0; j < B; ++j) {
            bF += (pF >= soff[j]) ? 1 : 0;
            bL += (pL >= soff[j]) ? 1 : 0;
        }
        fast = (bF == bL);
        bU = bF;
    }

    if (fast) {
        int q = qlo + t;
        int p0 = q % 3;
        float s0 = INFINITY, s1 = INFINITY, s2 = INFINITY;
        for (;;) {
            if (q >= qhi) break;
            float4 v = c4[q];
            s0 = fminf(s0, fminf(v.x, v.w)); s1 = fminf(s1, v.y); s2 = fminf(s2, v.z);
            q += 256;
            if (q >= qhi) break;
            v = c4[q];
            s1 = fminf(s1, fminf(v.x, v.w)); s2 = fminf(s2, v.y); s0 = fminf(s0, v.z);
            q += 256;
            if (q >= qhi) break;
            v = c4[q];
            s2 = fminf(s2, fminf(v.x, v.w)); s0 = fminf(s0, v.y); s1 = fminf(s1, v.z);
            q += 256;
        }
        float ax, ay, az;
        if (p0 == 0)      { ax = s0; ay = s1; az = s2; }
        else if (p0 == 1) { ax = s2; ay = s0; az = s1; }
        else              { ax = s1; ay = s2; az = s0; }
        for (int d = 32; d; d >>= 1) {
            ax = fminf(ax, __shfl_xor(ax, d));
            ay = fminf(ay, __shfl_xor(ay, d));
            az = fminf(az, __shfl_xor(az, d));
        }
        if ((t & 63) == 0 && ax < INFINITY) {
            atomicMin(&smin[bU * 3 + 0], f2m(ax));
            atomicMin(&smin[bU * 3 + 1], f2m(ay));
            atomicMin(&smin[bU * 3 + 2], f2m(az));
        }
    } else {
        for (int q = qlo + t; q < qhi; q += 256) {
            float4 v = c4[q];
            int e = 4 * q;
            float vals[4] = {v.x, v.y, v.z, v.w};
#pragma unroll
            for (int k = 0; k < 4; ++k) {
                int ee = e + k;
                int pt = ee / 3;
                int axis = ee - 3 * pt;
                int b = 0;
                for (int j = 0; j < B; ++j) b += (pt >= soff[j]) ? 1 : 0;
                atomicMin(&smin[b * 3 + axis], f2m(vals[k]));
            }
        }
    }

    if (blockIdx.x == 0) {
        for (int ee = 4 * NQ + t; ee < F; ee += 256) {
            int pt = ee / 3;
            int axis = ee - 3 * pt;
            int b = 0;
            for (int j = 0; j < B; ++j) b += (pt >= soff[j]) ? 1 : 0;
            atomicMin(&smin[b * 3 + axis], f2m(coord[ee]));
        }
    }
    __syncthreads();
    for (int j = t; j < nb3; j += 256) {
        uint mn = smin[j];
        if (mn != 0xFFFFFFFFu) atomicMin(&start_m[j], mn);
    }
}

// ---------------- partition pipeline ----------------

// full record for one point: [q:11 | cell:14 | ux:12 | uy:12 | uz:12]
__device__ __forceinline__ u64 mk_rec(float x, float y, float z,
                                      float sx, float sy, float sz,
                                      int b, uint& q) {
    int gx = min((int)floorf((x - sx) / VS), 127);
    int gy = min((int)floorf((y - sy) / VS), 127);
    int gz = min((int)floorf((z - sz) / VS), 127);
    float fx = fmaxf(x - (sx + (float)gx * VS), 0.0f);
    float fy = fmaxf(y - (sy + (float)gy * VS), 0.0f);
    float fz = fmaxf(z - (sz + (float)gz * VS), 0.0f);
    uint ux = min((uint)(fx * QSCALE + 0.5f), 4095u);
    uint uy = min((uint)(fy * QSCALE + 0.5f), 4095u);
    uint uz = min((uint)(fz * QSCALE + 0.5f), 4095u);
    uint cell = ((uint)gy << 7) | (uint)gz;
    q = ((uint)b << 7) | (uint)gx;
    return ((u64)q << 50) | ((u64)cell << 36) | ((u64)ux << 24) | ((u64)uy << 12) | (u64)uz;
}

__device__ __forceinline__ void count_point(float x, float y, float z, int b,
                                            float sx, float sy, float sz, int pid,
                                            uint* hist, u64* __restrict__ tmp) {
    uint q;
    u64 rec = mk_rec(x, y, z, sx, sy, sz, b, q);
    atomicAdd(&hist[q], 1u);        // LDS atomic only
    tmp[pid] = rec;                 // coalesced
}

// per-block LDS histogram -> TRANSPOSED histm[bucket][block]; writes tagged
// records coalesced to tmp. No global atomics.
__global__ void __launch_bounds__(1024)
k_count3(const float* __restrict__ coord, const int* __restrict__ offset,
         int N, int B, const uint* __restrict__ start_m, uint* __restrict__ histm,
         u64* __restrict__ tmp) {
    __shared__ uint hist[NBUCKET];
    __shared__ int soff[16];
    __shared__ float sstart[48];
    int t = threadIdx.x;
    if (t < B) soff[t] = offset[t];
    if (t < B * 3) sstart[t] = m2f(start_m[t]);
    for (int j = t; j < NBUCKET; j += 1024) hist[j] = 0;
    __syncthreads();
    int chunk = (N + gridDim.x - 1) / gridDim.x;
    int lo = blockIdx.x * chunk, hi = min(N, lo + chunk);
    int bLo = 0, bHi = 0;
    for (int j = 0; j < B; ++j) {
        bLo += (lo >= soff[j]) ? 1 : 0;
        bHi += (hi - 1 >= soff[j]) ? 1 : 0;
    }
    if (lo < hi && bLo == bHi && (lo & 3) == 0) {
        int b = bLo;
        float sx = sstart[b * 3 + 0], sy = sstart[b * 3 + 1], sz = sstart[b * 3 + 2];
        const float4* __restrict__ c4 = reinterpret_cast<const float4*>(coord);
        int gEnd = hi >> 2;
        for (int g = (lo >> 2) + t; g < gEnd; g += 1024) {
            float4 v0 = c4[3 * g], v1 = c4[3 * g + 1], v2 = c4[3 * g + 2];
            int p = 4 * g;
            count_point(v0.x, v0.y, v0.z, b, sx, sy, sz, p + 0, hist, tmp);
            count_point(v0.w, v1.x, v1.y, b, sx, sy, sz, p + 1, hist, tmp);
            count_point(v1.z, v1.w, v2.x, b, sx, sy, sz, p + 2, hist, tmp);
            count_point(v2.y, v2.z, v2.w, b, sx, sy, sz, p + 3, hist, tmp);
        }
        for (int i = (gEnd << 2) + t; i < hi; i += 1024) {
            float x = coord[3 * i + 0], y = coord[3 * i + 1], z = coord[3 * i + 2];
            count_point(x, y, z, b, sx, sy, sz, i, hist, tmp);
        }
    } else {
        for (int i = lo + t; i < hi; i += 1024) {
            float x = coord[3 * i + 0], y = coord[3 * i + 1], z = coord[3 * i + 2];
            int b = 0;
            for (int j = 0; j < B; ++j) b += (i >= soff[j]) ? 1 : 0;
            count_point(x, y, z, b, sstart[b * 3 + 0], sstart[b * 3 + 1],
                        sstart[b * 3 + 2], i, hist, tmp);
        }
    }
    __syncthreads();
    for (int j = t; j < NBUCKET; j += 1024)
        histm[(size_t)j * NBLK_P + blockIdx.x] = hist[j];
}

// per-bucket row scan (256 values): exclusive prefix in place + row total.
// shfl wave scan: 2 barriers.
__global__ void __launch_bounds__(256)
k_scanrow(uint* __restrict__ histm, uint* __restrict__ tot) {
    __shared__ uint wtot[4], woff[4];
    uint* row = histm + (size_t)blockIdx.x * NBLK_P;
    int t = threadIdx.x;
    uint v = row[t];
    uint sc = v;
    for (int d = 1; d < 64; d <<= 1) {
        uint nb = __shfl_up(sc, d, 64);
        if ((t & 63) >= d) sc += nb;
    }
    if ((t & 63) == 63) wtot[t >> 6] = sc;
    __syncthreads();
    if (t == 0) {
        uint r = 0;
#pragma unroll
        for (int k = 0; k < 4; ++k) { woff[k] = r; r += wtot[k]; }
    }
    __syncthreads();
    uint incl = sc + woff[t >> 6];
    row[t] = incl - v;
    if (t == 255) tot[blockIdx.x] = incl;
}

// exclusive scan of 2048 values -> out[0..2047], out[2048]=total. shfl scan.
__global__ void __launch_bounds__(1024)
k_scan2048(const uint* __restrict__ in, uint* __restrict__ out) {
    __shared__ uint wtot[16], woff[16];
    int t = threadIdx.x;
    uint a = in[2 * t], bb = in[2 * t + 1];
    uint s = a + bb;
    uint sc = s;
    for (int d = 1; d < 64; d <<= 1) {
        uint nb = __shfl_up(sc, d, 64);
        if ((t & 63) >= d) sc += nb;
    }
    if ((t & 63) == 63) wtot[t >> 6] = sc;
    __syncthreads();
    if (t == 0) {
        uint r = 0;
#pragma unroll
        for (int k = 0; k < 16; ++k) { woff[k] = r; r += wtot[k]; }
    }
    __syncthreads();
    uint incl = sc + woff[t >> 6];
    uint ex = incl - s;
    out[2 * t] = ex;
    out[2 * t + 1] = ex + a;
    if (t == 1023) out[2048] = incl;
}

// scan variant for voxcount -> voxscan, with n_o fused:
// no_out[b] = voxscan[(b+1)*128] = inclusive pair-sum at thread (b+1)*64-1
__global__ void __launch_bounds__(1024)
k_scan2048b(const uint* __restrict__ in, uint* __restrict__ out,
            int B, float* __restrict__ no_out) {
    __shared__ uint wtot[16], woff[16];
    int t = threadIdx.x;
    uint a = in[2 * t], bb = in[2 * t + 1];
    uint s = a + bb;
    uint sc = s;
    for (int d = 1; d < 64; d <<= 1) {
        uint nb = __shfl_up(sc, d, 64);
        if ((t & 63) >= d) sc += nb;
    }
    if ((t & 63) == 63) wtot[t >> 6] = sc;
    __syncthreads();
    if (t == 0) {
        uint r = 0;
#pragma unroll
        for (int k = 0; k < 16; ++k) { woff[k] = r; r += wtot[k]; }
    }
    __syncthreads();
    uint incl = sc + woff[t >> 6];
    uint ex = incl - s;
    out[2 * t] = ex;
    out[2 * t + 1] = ex + a;
    if (t == 1023) out[2048] = incl;
    int tp = t + 1;
    if ((tp & 63) == 0) {              // incl covers elements [0, 2*tp)
        int b = (tp >> 6) - 1;         // 2*tp == (b+1)*128
        if (b < B) no_out[b] = (float)incl;
    }
}

// scatter tagged records from tmp (L2/L3-resident) to bucket-grouped recs
__global__ void __launch_bounds__(1024)
k_scatter(const u64* __restrict__ tmp, int N,
          const uint* __restrict__ histm, const uint* __restrict__ bucket_base,
          u64* __restrict__ recs) {
    __shared__ uint cursor[NBUCKET];
    int t = threadIdx.x;
    for (int j = t; j < NBUCKET; j += 1024)
        cursor[j] = bucket_base[j] + histm[(size_t)j * NBLK_P + blockIdx.x];
    __syncthreads();
    int chunk = (N + gridDim.x - 1) / gridDim.x;
    int lo = blockIdx.x * chunk, hi = min(N, lo + chunk);
    for (int i = lo + t; i < hi; i += 1024) {
        u64 r = tmp[i];
        uint q = (uint)(r >> 50);
        uint slot = atomicAdd(&cursor[q], 1u);   // LDS atomic only
        recs[slot] = r;
    }
}

// per-bucket occupancy: voxcount + store mask to global (recs read = L3 hit).
__global__ void __launch_bounds__(256)
k_vox(const u64* __restrict__ recs, const uint* __restrict__ bucket_base,
      uint* __restrict__ voxcount, uint* __restrict__ gmask) {
    __shared__ uint bits[512];
    __shared__ uint wsum[4];
    int q = blockIdx.x;
    int t = threadIdx.x;
    uint lo = bucket_base[q], hi = bucket_base[q + 1];
    bits[t] = 0;
    bits[t + 256] = 0;
    __syncthreads();
    for (uint i = lo + t; i < hi; i += 256) {
        uint c = (uint)(recs[i] >> 36) & 0x3FFFu;
        atomicOr(&bits[c >> 5], 1u << (c & 31));   // LDS atomic only
    }
    __syncthreads();
    uint m0 = bits[t], m1 = bits[t + 256];
    gmask[(size_t)q * 512 + t] = m0;
    gmask[(size_t)q * 512 + t + 256] = m1;
    uint s = __popc(m0) + __popc(m1);
    for (int d = 32; d; d >>= 1) s += __shfl_xor(s, d);
    if ((t & 63) == 0) wsum[t >> 6] = s;
    __syncthreads();
    if (t == 0) voxcount[q] = wsum[0] + wsum[1] + wsum[2] + wsum[3];
}

// rank-dense emit (blocks < NBUCKET) + fused output-tail zeroing (blocks >=
// NBUCKET). Rank-parallel coalesced emit via precomputed cellOf[rank] (u16,
// owner bit-walk during dense-zero). lo/hi/base_r from precomputed
// bucket_base/voxscan -- NO in-block global reductions (R19 lesson).
__global__ void __launch_bounds__(1024)
k_emit2(const u64* __restrict__ recs, const uint* __restrict__ bucket_base,
        const uint* __restrict__ voxscan, const uint* __restrict__ gmask,
        const uint* __restrict__ start_m, int N, int B, int out_total,
        float* __restrict__ np_out, float* __restrict__ cnt_out,
        float* __restrict__ out) {
    int t = threadIdx.x;
    if (blockIdx.x >= NBUCKET) {
        uint total = voxscan[NBUCKET];
        int zb = blockIdx.x - NBUCKET;
        int stride = (gridDim.x - NBUCKET) * 1024;
        int tid = zb * 1024 + t;
        for (int j = 3 * (int)total + tid; j < 3 * N; j += stride) np_out[j] = 0.0f;
        for (int j = (int)total + tid; j < N; j += stride) cnt_out[j] = 0.0f;
        for (int j = 4 * N + B + tid; j < out_total; j += stride) out[j] = 0.0f;
        return;
    }
    __shared__ u64 dense[DENSE_MAX];    // 32 KB
    __shared__ uint mask[512], wrank[512];
    __shared__ u16 cellOf[DENSE_MAX];   // 8 KB
    __shared__ uint wtot[8], woff[9];
    __shared__ float sstart[48];
    int q = blockIdx.x;
    uint lo = bucket_base[q], hi = bucket_base[q + 1];
    if (lo == hi) return;
    if (t < 48) sstart[t] = m2f(start_m[t]);
    uint m = 0, c = 0;
    if (t < 512) {
        m = gmask[(size_t)q * 512 + t];
        mask[t] = m;
        c = __popc(m);
    }
    uint sc = c;
    for (int d = 1; d < 64; d <<= 1) {
        uint nb = __shfl_up(sc, d, 64);
        if ((t & 63) >= d) sc += nb;
    }
    if (t < 512 && (t & 63) == 63) wtot[t >> 6] = sc;
    __syncthreads();
    if (t == 0) {
        uint r = 0;
        for (int k = 0; k < 8; ++k) { woff[k] = r; r += wtot[k]; }
        woff[8] = r;
    }
    __syncthreads();
    uint myrank = sc - c + ((t < 512) ? woff[t >> 6] : 0);
    if (t < 512) wrank[t] = myrank;     // exclusive word rank
    uint vc = woff[8];
    uint base_r = voxscan[q];
    int b = q >> 7, gx = q & 127;
    float cx = sstart[b * 3 + 0] + (float)gx * VS;
    float sy = sstart[b * 3 + 1], sz = sstart[b * 3 + 2];
    for (uint segbase = 0; segbase < vc; segbase += DENSE_MAX) {
        uint seglen = min(vc - segbase, (uint)DENSE_MAX);
        for (uint j = t; j < seglen; j += 1024) dense[j] = 0ull;
        // owner-walk: build cellOf for this segment (u16 LDS writes, disjoint)
        if (t < 512) {
            uint mm = m;
            uint r = myrank;
            uint kbase = (uint)t << 5;
            while (mm) {
                uint bit = (uint)__ffs(mm) - 1u;
                mm &= mm - 1u;
                if (r >= segbase && r < segbase + seglen)
                    cellOf[r - segbase] = (u16)(kbase + bit);
                ++r;
            }
        }
        __syncthreads();                 // publishes dense-zero + cellOf + wrank/mask
        for (uint i = lo + t; i < hi; i += 1024) {
            u64 rec = recs[i];
            uint cc = (uint)(rec >> 36) & 0x3FFFu;
            uint w = cc >> 5, bit = cc & 31;
            uint r = wrank[w] + __popc(mask[w] & ((1u << bit) - 1u));
            if (r >= segbase && r < segbase + seglen) {
                u64 enc = (((rec >> 24) & 0xFFFull) << 46) | (((rec >> 12) & 0xFFFull) << 28)
                        | ((rec & 0xFFFull) << 10) | 1ull;
                atomicAdd(&dense[r - segbase], enc);
            }
        }
        __syncthreads();
        // rank-parallel coalesced emit: 1 stride-1 u16 LDS read per rank
        for (uint rr = segbase + t; rr < segbase + seglen; rr += 1024) {
            uint cell = cellOf[rr - segbase];
            uint gy = cell >> 7, gz = cell & 127u;
            u64 p = dense[rr - segbase];
            float cnt = (float)(uint)(p & 1023ull);
            float inv = 1.0f / fmaxf(cnt, 1.0f);
            uint uz = (uint)((p >> 10) & 0x3FFFFull);
            uint uy = (uint)((p >> 28) & 0x3FFFFull);
            uint ux = (uint)(p >> 46);
            uint r_out = base_r + rr;
            np_out[3 * r_out + 0] = cx + ((float)ux * QINV) * inv;
            np_out[3 * r_out + 1] = sy + (float)gy * VS + ((float)uy * QINV) * inv;
            np_out[3 * r_out + 2] = sz + (float)gz * VS + ((float)uz * QINV) * inv;
            cnt_out[r_out] = cnt;
        }
        __syncthreads();
    }
}

// ---------------- sparse fallback (G-free keys) ----------------

__device__ __forceinline__ void point_grid(const float* __restrict__ coord, int i,
                                           const int* soff, const float* sstart, int B,
                                           float& x, float& y, float& z,
                                           int& b, int& gx, int& gy, int& gz) {
    x = coord[3 * i + 0]; y = coord[3 * i + 1]; z = coord[3 * i + 2];
    b = 0;
    for (int j = 0; j < B; ++j) b += (i >= soff[j]) ? 1 : 0;
    gx = min((int)floorf((x - sstart[b * 3 + 0]) / VS), 127);
    gy = min((int)floorf((y - sstart[b * 3 + 1]) / VS), 127);
    gz = min((int)floorf((z - sstart[b * 3 + 2]) / VS), 127);
}

__device__ __forceinline__ u64 frac12(float x, float y, float z,
                                      const float* sstart, int b,
                                      int gx, int gy, int gz) {
    float fx = fmaxf(x - (sstart[b * 3 + 0] + (float)gx * VS), 0.0f);
    float fy = fmaxf(y - (sstart[b * 3 + 1] + (float)gy * VS), 0.0f);
    float fz = fmaxf(z - (sstart[b * 3 + 2] + (float)gz * VS), 0.0f);
    uint ux = min((uint)(fx * QSCALE + 0.5f), 4095u);
    uint uy = min((uint)(fy * QSCALE + 0.5f), 4095u);
    uint uz = min((uint)(fz * QSCALE + 0.5f), 4095u);
    return ((u64)ux << 24) | ((u64)uy << 12) | (u64)uz;
}

__global__ void k_hist(const float* __restrict__ coord, const int* __restrict__ offset,
                       int N, int B, const uint* __restrict__ start_m,
                       uint* __restrict__ mask) {
    __shared__ int soff[256];
    __shared__ float sstart[768];
    for (int j = threadIdx.x; j < B; j += blockDim.x) soff[j] = offset[j];
    for (int j = threadIdx.x; j < B * 3; j += blockDim.x) sstart[j] = m2f(start_m[j]);
    __syncthreads();
    int i = blockIdx.x * blockDim.x + threadIdx.x;
    if (i >= N) return;
    float x, y, z; int b, gx, gy, gz;
    point_grid(coord, i, soff, sstart, B, x, y, z, b, gx, gy, gz);
    uint key = ((uint)b << 21) | ((uint)gx << 14) | ((uint)gy << 7) | (uint)gz;
    atomicOr(&mask[key >> 5], 1u << (key & 31));
}

__global__ void k_scan1(const uint* __restrict__ mask, uint* __restrict__ partial) {
    int base = blockIdx.x * 1024 + threadIdx.x * 4;
    uint4 m = *(const uint4*)(mask + base);
    uint s = __popc(m.x) + __popc(m.y) + __popc(m.z) + __popc(m.w);
    for (int d = 32; d; d >>= 1) s += __shfl_xor(s, d);
    __shared__ uint wsum[4];
    if ((threadIdx.x & 63) == 0) wsum[threadIdx.x >> 6] = s;
    __syncthreads();
    if (threadIdx.x == 0) partial[blockIdx.x] = wsum[0] + wsum[1] + wsum[2] + wsum[3];
}

__global__ void k_scan2(uint* partial, int P, uint* total) {
    __shared__ uint t[256];
    uint carry = 0;
    for (int base = 0; base < P; base += 256) {
        int j = base + threadIdx.x;
        uint v = (j < P) ? partial[j] : 0;
        t[threadIdx.x] = v;
        __syncthreads();
        for (int d = 1; d < 256; d <<= 1) {
            uint add = (threadIdx.x >= d) ? t[threadIdx.x - d] : 0;
            __syncthreads();
            t[threadIdx.x] += add;
            __syncthreads();
        }
        uint inc = t[threadIdx.x];
        uint chunk = t[255];
        if (j < P) partial[j] = carry + inc - v;
        __syncthreads();
        carry += chunk;
    }
    if (threadIdx.x == 0) *total = carry;
}

__global__ void k_scan3(const uint* __restrict__ mask, const uint* __restrict__ partial,
                        uint* __restrict__ wordrank) {
    int base = blockIdx.x * 1024 + threadIdx.x * 4;
    uint4 m = *(const uint4*)(mask + base);
    uint c0 = __popc(m.x), c1 = __popc(m.y), c2 = __popc(m.z), c3 = __popc(m.w);
    uint s = c0 + c1 + c2 + c3;
    __shared__ uint t[256];
    t[threadIdx.x] = s;
    __syncthreads();
    for (int d = 1; d < 256; d <<= 1) {
        uint add = (threadIdx.x >= d) ? t[threadIdx.x - d] : 0;
        __syncthreads();
        t[threadIdx.x] += add;
        __syncthreads();
    }
    uint ex = t[threadIdx.x] - s + partial[blockIdx.x];
    uint4 r;
    r.x = ex; r.y = ex + c0; r.z = ex + c0 + c1; r.w = ex + c0 + c1 + c2;
    *(uint4*)(wordrank + base) = r;
}

__global__ void k_no(const uint* mask, const uint* wordrank, const uint* total,
                     float* no_out, int B, int W) {
    int b = blockIdx.x * blockDim.x + threadIdx.x;
    if (b >= B) return;
    long long idx = (long long)(b + 1) << 21;
    uint w = (uint)(idx >> 5);
    uint v;
    if (w >= (uint)W) v = *total;
    else v = wordrank[w];
    no_out[b] = (float)v;
}

__global__ void k_accum_sparse(const float* __restrict__ coord, const int* __restrict__ offset,
                               int N, int B, const uint* __restrict__ start_m,
                               const uint* __restrict__ mask, const uint* __restrict__ wordrank,
                               u64* __restrict__ packed) {
    __shared__ int soff[256];
    __shared__ float sstart[768];
    for (int j = threadIdx.x; j < B; j += blockDim.x) soff[j] = offset[j];
    for (int j = threadIdx.x; j < B * 3; j += blockDim.x) sstart[j] = m2f(start_m[j]);
    __syncthreads();
    int i = blockIdx.x * blockDim.x + threadIdx.x;
    if (i >= N) return;
    float x, y, z; int b, gx, gy, gz;
    point_grid(coord, i, soff, sstart, B, x, y, z, b, gx, gy, gz);
    uint key = ((uint)b << 21) | ((uint)gx << 14) | ((uint)gy << 7) | (uint)gz;
    uint w = key >> 5, bit = key & 31;
    uint r = wordrank[w] + __popc(mask[w] & ((1u << bit) - 1u));
    u64 f = frac12(x, y, z, sstart, b, gx, gy, gz);
    u64 enc = (((f >> 24) & 0xFFFull) << 46) | (((f >> 12) & 0xFFFull) << 28)
            | ((f & 0xFFFull) << 10) | 1ull;
    atomicAdd(&packed[r], enc);
}

__global__ void k_decode_sparse(const uint* __restrict__ mask, const uint* __restrict__ wordrank,
                                const uint* __restrict__ start_m,
                                const u64* __restrict__ packed, int W,
                                float* __restrict__ np_out, float* __restrict__ cnt_out) {
    __shared__ float sstart[48];
    for (int j = threadIdx.x; j < 48; j += blockDim.x) sstart[j] = m2f(start_m[j]);
    __syncthreads();
    int w = blockIdx.x * blockDim.x + threadIdx.x;
    if (w >= W) return;
    uint m = mask[w];
    if (m == 0) return;
    uint r = wordrank[w];
    uint kbase = (uint)w << 5;
    while (m) {
        uint bit = (uint)__ffs(m) - 1u;
        m &= m - 1u;
        uint key = kbase + bit;
        u64 p = packed[r];
        float cnt = (float)(uint)(p & 1023ull);
        float inv = 1.0f / fmaxf(cnt, 1.0f);
        uint uz = (uint)((p >> 10) & 0x3FFFFull);
        uint uy = (uint)((p >> 28) & 0x3FFFFull);
        uint ux = (uint)(p >> 46);
        uint b = key >> 21;
        uint gx = (key >> 14) & 127u;
        uint gy = (key >> 7) & 127u;
        uint gz = key & 127u;
        np_out[3 * r + 0] = sstart[b * 3 + 0] + (float)gx * VS + ((float)ux * QINV) * inv;
        np_out[3 * r + 1] = sstart[b * 3 + 1] + (float)gy * VS + ((float)uy * QINV) * inv;
        np_out[3 * r + 2] = sstart[b * 3 + 2] + (float)gz * VS + ((float)uz * QINV) * inv;
        cnt_out[r] = cnt;
        ++r;
    }
}

extern "C" void kernel_launch(void* const* d_in, const int* in_sizes, int n_in,
                              void* d_out, int out_size, void* d_ws, size_t ws_size,
                              hipStream_t stream) {
    const float* coord = (const float*)d_in[0];
    const int* offset = (const int*)d_in[1];
    int N = in_sizes[0] / 3;
    int B = in_sizes[1];

    float* out = (float*)d_out;
    float* np_out = out;                       // [N,3]
    float* no_out = out + (size_t)3 * N;       // [B]
    float* cnt_out = no_out + B;               // [N]

    uint8_t* base = (uint8_t*)d_ws;
    uint* start_m = (uint*)base;
    uint* total = start_m + (size_t)B * 3;

    // partition-path layout
    uintptr_t p = (uintptr_t)(total + 1);
    p = (p + 255) & ~(uintptr_t)255;
    uint* histm = (uint*)p;          p += (size_t)NBUCKET * NBLK_P * 4;   // 2MB
    p = (p + 255) & ~(uintptr_t)255;
    uint* tot = (uint*)p;            p += (size_t)NBUCKET * 4;
    p = (p + 255) & ~(uintptr_t)255;
    uint* bucket_base = (uint*)p;    p += (size_t)(NBUCKET + 1) * 4;
    p = (p + 255) & ~(uintptr_t)255;
    uint* voxcount = (uint*)p;       p += (size_t)NBUCKET * 4;
    p = (p + 255) & ~(uintptr_t)255;
    uint* voxscan = (uint*)p;        p += (size_t)(NBUCKET + 1) * 4;
    p = (p + 255) & ~(uintptr_t)255;
    uint* gmask = (uint*)p;          p += (size_t)NBUCKET * 512 * 4;      // 4MB
    p = (p + 255) & ~(uintptr_t)255;
    u64* recs = (u64*)p;             p += (size_t)N * 8;                  // 33MB
    p = (p + 255) & ~(uintptr_t)255;
    u64* tmp = (u64*)p;              p += (size_t)N * 8;                  // 33MB
    size_t need_part = p - (uintptr_t)base;

    k_init<<<(B * 3 + 255) / 256, 256, 0, stream>>>(start_m, B * 3);
    k_minmax<<<2048, 256, 0, stream>>>(coord, offset, N, B, start_m);

    if (B <= 16 && ws_size >= need_part) {
        k_count3<<<NBLK_P, 1024, 0, stream>>>(coord, offset, N, B, start_m, histm, tmp);
        k_scanrow<<<NBUCKET, 256, 0, stream>>>(histm, tot);
        k_scan2048<<<1, 1024, 0, stream>>>(tot, bucket_base);
        k_scatter<<<NBLK_P, 1024, 0, stream>>>(tmp, N, histm, bucket_base, recs);
        k_vox<<<NBUCKET, 256, 0, stream>>>(recs, bucket_base, voxcount, gmask);
        k_scan2048b<<<1, 1024, 0, stream>>>(voxcount, voxscan, B, no_out);
        k_emit2<<<NBUCKET + 1024, 1024, 0, stream>>>(recs, bucket_base, voxscan, gmask,
                                                     start_m, N, B, out_size,
                                                     np_out, cnt_out, out);
    } else {
        // sparse fallback: G-free 128-stride keys, mask over B*2^21 bits
        hipMemsetAsync(d_out, 0, (size_t)out_size * sizeof(float), stream);
        size_t W = (size_t)B << 16;
        int nblk1 = (int)(W / 1024);
        uintptr_t sp = (uintptr_t)(total + 1);
        sp = (sp + 255) & ~(uintptr_t)255;
        uint* partial = (uint*)sp;   sp += (size_t)nblk1 * 4;
        sp = (sp + 255) & ~(uintptr_t)255;
        uint* mask = (uint*)sp;      sp += W * 4;
        sp = (sp + 255) & ~(uintptr_t)255;
        uint* wordrank = (uint*)sp;  sp += W * 4;
        sp = (sp + 255) & ~(uintptr_t)255;
        u64* packed = (u64*)sp;
        int nb = (N + 255) / 256;
        hipMemsetAsync(mask, 0, W * sizeof(uint), stream);
        hipMemsetAsync(packed, 0, (size_t)N * sizeof(u64), stream);
        k_hist<<<nb, 256, 0, stream>>>(coord, offset, N, B, start_m, mask);
        k_scan1<<<nblk1, 256, 0, stream>>>(mask, partial);
        k_scan2<<<1, 256, 0, stream>>>(partial, nblk1, total);
        k_scan3<<<nblk1, 256, 0, stream>>>(mask, partial, wordrank);
        k_no<<<(B + 63) / 64, 64, 0, stream>>>(mask, wordrank, total, no_out, B, (int)W);
        k_accum_sparse<<<nb, 256, 0, stream>>>(coord, offset, N, B, start_m, mask,
                                               wordrank, packed);
        k_decode_sparse<<<(int)((W + 255) / 256), 256, 0, stream>>>(mask, wordrank, start_m,
                                                                    packed, (int)W,
                                                                    np_out, cnt_out);
    }
}